// Round 11
// baseline (250.015 us; speedup 1.0000x reference)
//
#include <hip/hip_runtime.h>
#include <hip/hip_bf16.h>
#include <math.h>

#define N_TOK 131072
#define HD    256
#define DS    32
#define DG    32
#define FM    64
#define NE    4
#define FF    512
#define MT    64   // tokens per expert block (8 waves, 512 threads)

typedef short    short8 __attribute__((ext_vector_type(8)));
typedef _Float16 f16x8  __attribute__((ext_vector_type(8)));
typedef float    f32x4  __attribute__((ext_vector_type(4)));

struct F16Pair { _Float16 hi, lo; };

__device__ __forceinline__ float gelu_f(float x) {        // exact erf (router)
    return 0.5f * x * (1.0f + erff(x * 0.70710678118654752f));
}
__device__ __forceinline__ float gelu_s(float x) {        // sigmoid approx (expert)
    float t = __expf(-1.702f * x);
    return x * __builtin_amdgcn_rcpf(1.0f + t);
}
__device__ __forceinline__ unsigned short f2bf(float x) {
    union { __hip_bfloat16 b; unsigned short u; } cv;
    cv.b = __float2bfloat16(x);
    return cv.u;
}
__device__ __forceinline__ F16Pair split16(float v) {
    F16Pair p;
    p.hi = (_Float16)v;
    p.lo = (_Float16)(v - (float)p.hi);
    return p;
}

// ---------------------------------------------------------------------------
// Prep (fused): blocks 0..511 repack expert weights (frag-ordered bf16);
// blocks 512..518 build router fp16 hi/lo tables + folded gb2.
// ---------------------------------------------------------------------------
__global__ __launch_bounds__(256) void prep_all_kernel(
    const float* __restrict__ w1, const float* __restrict__ w2,
    unsigned short* __restrict__ w1p, unsigned short* __restrict__ w2p,
    const float* __restrict__ geom_w, const float* __restrict__ geom_b,
    const float* __restrict__ ln_g, const float* __restrict__ ln_b,
    const float* __restrict__ fuse_w, const float* __restrict__ router_w,
    _Float16* __restrict__ wg_hi, _Float16* __restrict__ wg_lo,
    _Float16* __restrict__ wf_hi, _Float16* __restrict__ wf_lo,
    _Float16* __restrict__ wr_hi, _Float16* __restrict__ wr_lo,
    float* __restrict__ gb2)
{
    if (blockIdx.x < 512) {
        int t = (blockIdx.x & 255) * 256 + threadIdx.x;
        const int lane = t & 63;
        const int kg   = lane >> 4;
        const int row  = lane & 15;
        if (blockIdx.x < 256) {
            const int ni = (t >> 6) & 31;
            const int ks = (t >> 11) & 7;
            const int e  = t >> 14;
            const int n  = ni * 16 + row;
            const int k0 = ks * 32 + kg * 8;
            short8 o;
            #pragma unroll
            for (int j = 0; j < 8; ++j)
                o[j] = (short)f2bf(w1[((size_t)e * HD + k0 + j) * FF + n]);
            *reinterpret_cast<short8*>(&w1p[(size_t)(((e*8 + ks)*32 + ni)*64 + lane) * 8]) = o;
        } else {
            const int ni = (t >> 6) & 15;
            const int ks = (t >> 10) & 15;
            const int e  = t >> 14;
            const int n  = ni * 16 + row;
            const int k0 = ks * 32 + kg * 8;
            short8 o;
            #pragma unroll
            for (int j = 0; j < 8; ++j)
                o[j] = (short)f2bf(w2[((size_t)e * FF + k0 + j) * HD + n]);
            *reinterpret_cast<short8*>(&w2p[(size_t)(((e*16 + ks)*16 + ni)*64 + lane) * 8]) = o;
        }
        return;
    }
    const int slot = (blockIdx.x - 512) * 256 + threadIdx.x;
    const int lane = slot & 63;
    const int kg   = lane >> 4;
    const int row  = lane & 15;
    if (slot < 1024) {
        const int f = slot >> 6, ks = f >> 1, ni = f & 1;
        const int n = ni * 16 + row;
        f16x8 hi, lo;
        #pragma unroll
        for (int j = 0; j < 8; ++j) {
            int k = ks * 32 + kg * 8 + j;
            F16Pair p = split16(ln_g[k] * geom_w[k * DG + n]);
            hi[j] = p.hi; lo[j] = p.lo;
        }
        *reinterpret_cast<f16x8*>(&wg_hi[(size_t)slot * 8]) = hi;
        *reinterpret_cast<f16x8*>(&wg_lo[(size_t)slot * 8]) = lo;
    } else if (slot < 1536) {
        const int s = slot - 1024;
        const int f = s >> 6, ks = f >> 2, ni = f & 3;
        const int n = ni * 16 + row;
        f16x8 hi, lo;
        #pragma unroll
        for (int j = 0; j < 8; ++j) {
            int k = ks * 32 + kg * 8 + j;
            F16Pair p = split16(fuse_w[k * FM + n]);
            hi[j] = p.hi; lo[j] = p.lo;
        }
        *reinterpret_cast<f16x8*>(&wf_hi[(size_t)s * 8]) = hi;
        *reinterpret_cast<f16x8*>(&wf_lo[(size_t)s * 8]) = lo;
    } else if (slot < 1664) {
        const int s = slot - 1536;
        const int ks = s >> 6;
        f16x8 hi, lo;
        #pragma unroll
        for (int j = 0; j < 8; ++j) {
            int k = ks * 32 + kg * 8 + j;
            F16Pair p = split16((row < NE) ? router_w[k * NE + row] : 0.f);
            hi[j] = p.hi; lo[j] = p.lo;
        }
        *reinterpret_cast<f16x8*>(&wr_hi[(size_t)s * 8]) = hi;
        *reinterpret_cast<f16x8*>(&wr_lo[(size_t)s * 8]) = lo;
    } else if (slot < 1696) {
        const int n = slot - 1664;   // 0..31
        float acc = geom_b[n];
        for (int k = 0; k < HD; ++k) acc += ln_b[k] * geom_w[k * DG + n];
        gb2[n] = acc;
    }
}

// ---------------------------------------------------------------------------
// Router v3 (MFMA + fused bucketing) — round-9 version, verified.
// ---------------------------------------------------------------------------
__global__ __launch_bounds__(256) void router3_kernel(
    const float* __restrict__ h, const float* __restrict__ tok_emb,
    const _Float16* __restrict__ wg_hi, const _Float16* __restrict__ wg_lo,
    const _Float16* __restrict__ wf_hi, const _Float16* __restrict__ wf_lo,
    const _Float16* __restrict__ wr_hi, const _Float16* __restrict__ wr_lo,
    const float* __restrict__ gb2, const float* __restrict__ fuse_b,
    const float* __restrict__ router_b,
    float* __restrict__ top_prob, int* __restrict__ order,
    int* __restrict__ counts, float* __restrict__ importance)
{
    __shared__ __align__(16) _Float16 sg_hi[4][16][40], sg_lo[4][16][40];
    __shared__ __align__(16) _Float16 su_hi[4][16][72], su_lo[4][16][72];
    __shared__ __align__(16) float    s_lg[4][16][4];
    __shared__ float s_imp[NE];
    __shared__ int   s_cnt[NE];
    __shared__ int   s_base[NE];

    const int tid  = threadIdx.x;
    const int wv   = tid >> 6;
    const int lane = tid & 63;
    const int kg   = lane >> 4;
    const int row  = lane & 15;
    const int tok  = blockIdx.x * 64 + wv * 16 + row;

    if (tid < NE) { s_imp[tid] = 0.f; s_cnt[tid] = 0; }
    __syncthreads();

    const float* hrow = h + (size_t)tok * HD;
    float s1 = 0.f, s2 = 0.f;
    #pragma unroll
    for (int ks = 0; ks < 8; ++ks) {
        float4 x0 = *reinterpret_cast<const float4*>(hrow + ks * 32 + kg * 8);
        float4 x1 = *reinterpret_cast<const float4*>(hrow + ks * 32 + kg * 8 + 4);
        s1 += (x0.x + x0.y) + (x0.z + x0.w) + (x1.x + x1.y) + (x1.z + x1.w);
        s2 += x0.x*x0.x + x0.y*x0.y + x0.z*x0.z + x0.w*x0.w
            + x1.x*x1.x + x1.y*x1.y + x1.z*x1.z + x1.w*x1.w;
    }
    s1 += __shfl_xor(s1, 16); s1 += __shfl_xor(s1, 32);
    s2 += __shfl_xor(s2, 16); s2 += __shfl_xor(s2, 32);
    const float mu   = s1 * (1.0f / HD);
    const float var  = s2 * (1.0f / HD) - mu * mu;
    const float rstd = rsqrtf(var + 1e-5f);

    f16x8 ahi[8], alo[8];
    #pragma unroll
    for (int ks = 0; ks < 8; ++ks) {
        float4 x0 = *reinterpret_cast<const float4*>(hrow + ks * 32 + kg * 8);
        float4 x1 = *reinterpret_cast<const float4*>(hrow + ks * 32 + kg * 8 + 4);
        float v[8] = {x0.x, x0.y, x0.z, x0.w, x1.x, x1.y, x1.z, x1.w};
        #pragma unroll
        for (int j = 0; j < 8; ++j) {
            F16Pair p = split16((v[j] - mu) * rstd);
            ahi[ks][j] = p.hi; alo[ks][j] = p.lo;
        }
    }

    const f16x8* WGH = reinterpret_cast<const f16x8*>(wg_hi);
    const f16x8* WGL = reinterpret_cast<const f16x8*>(wg_lo);
    f32x4 accg[2];
    #pragma unroll
    for (int ni = 0; ni < 2; ++ni) {
        float bb = gb2[ni * 16 + row];
        accg[ni] = (f32x4){bb, bb, bb, bb};
    }
    #pragma unroll
    for (int ks = 0; ks < 8; ++ks) {
        #pragma unroll
        for (int ni = 0; ni < 2; ++ni) {
            f16x8 bh = WGH[(ks * 2 + ni) * 64 + lane];
            f16x8 bl = WGL[(ks * 2 + ni) * 64 + lane];
            accg[ni] = __builtin_amdgcn_mfma_f32_16x16x32_f16(ahi[ks], bh, accg[ni], 0, 0, 0);
            accg[ni] = __builtin_amdgcn_mfma_f32_16x16x32_f16(alo[ks], bh, accg[ni], 0, 0, 0);
            accg[ni] = __builtin_amdgcn_mfma_f32_16x16x32_f16(ahi[ks], bl, accg[ni], 0, 0, 0);
        }
    }
    #pragma unroll
    for (int ni = 0; ni < 2; ++ni)
        #pragma unroll
        for (int r = 0; r < 4; ++r) {
            F16Pair p = split16(gelu_f(accg[ni][r]));
            sg_hi[wv][kg * 4 + r][ni * 16 + row] = p.hi;
            sg_lo[wv][kg * 4 + r][ni * 16 + row] = p.lo;
        }

    f16x8 a2h[2], a2l[2];
    {
        const float* terow = tok_emb + (size_t)tok * DS;
        float4 x0 = *reinterpret_cast<const float4*>(terow + kg * 8);
        float4 x1 = *reinterpret_cast<const float4*>(terow + kg * 8 + 4);
        float v[8] = {x0.x, x0.y, x0.z, x0.w, x1.x, x1.y, x1.z, x1.w};
        #pragma unroll
        for (int j = 0; j < 8; ++j) {
            F16Pair p = split16(v[j]);
            a2h[0][j] = p.hi; a2l[0][j] = p.lo;
        }
        a2h[1] = *reinterpret_cast<const f16x8*>(&sg_hi[wv][row][kg * 8]);
        a2l[1] = *reinterpret_cast<const f16x8*>(&sg_lo[wv][row][kg * 8]);
    }
    const f16x8* WFH = reinterpret_cast<const f16x8*>(wf_hi);
    const f16x8* WFL = reinterpret_cast<const f16x8*>(wf_lo);
    f32x4 accf[4];
    #pragma unroll
    for (int ni = 0; ni < 4; ++ni) {
        float bb = fuse_b[ni * 16 + row];
        accf[ni] = (f32x4){bb, bb, bb, bb};
    }
    #pragma unroll
    for (int ks = 0; ks < 2; ++ks) {
        #pragma unroll
        for (int ni = 0; ni < 4; ++ni) {
            f16x8 bh = WFH[(ks * 4 + ni) * 64 + lane];
            f16x8 bl = WFL[(ks * 4 + ni) * 64 + lane];
            accf[ni] = __builtin_amdgcn_mfma_f32_16x16x32_f16(a2h[ks], bh, accf[ni], 0, 0, 0);
            accf[ni] = __builtin_amdgcn_mfma_f32_16x16x32_f16(a2l[ks], bh, accf[ni], 0, 0, 0);
            accf[ni] = __builtin_amdgcn_mfma_f32_16x16x32_f16(a2h[ks], bl, accf[ni], 0, 0, 0);
        }
    }
    #pragma unroll
    for (int ni = 0; ni < 4; ++ni)
        #pragma unroll
        for (int r = 0; r < 4; ++r) {
            F16Pair p = split16(gelu_f(accf[ni][r]));
            su_hi[wv][kg * 4 + r][ni * 16 + row] = p.hi;
            su_lo[wv][kg * 4 + r][ni * 16 + row] = p.lo;
        }

    const f16x8* WRH = reinterpret_cast<const f16x8*>(wr_hi);
    const f16x8* WRL = reinterpret_cast<const f16x8*>(wr_lo);
    f32x4 accl = (f32x4){0.f, 0.f, 0.f, 0.f};
    #pragma unroll
    for (int ks = 0; ks < 2; ++ks) {
        f16x8 a3h = *reinterpret_cast<const f16x8*>(&su_hi[wv][row][ks * 32 + kg * 8]);
        f16x8 a3l = *reinterpret_cast<const f16x8*>(&su_lo[wv][row][ks * 32 + kg * 8]);
        f16x8 bh = WRH[ks * 64 + lane];
        f16x8 bl = WRL[ks * 64 + lane];
        accl = __builtin_amdgcn_mfma_f32_16x16x32_f16(a3h, bh, accl, 0, 0, 0);
        accl = __builtin_amdgcn_mfma_f32_16x16x32_f16(a3l, bh, accl, 0, 0, 0);
        accl = __builtin_amdgcn_mfma_f32_16x16x32_f16(a3h, bl, accl, 0, 0, 0);
    }
    if (row < NE) {
        float rb = router_b[row];
        #pragma unroll
        for (int r = 0; r < 4; ++r)
            s_lg[wv][kg * 4 + r][row] = accl[r] + rb;
    }
    __syncthreads();

    int bi = 0, rk = 0, gt = 0;
    if (lane < 16) {
        float4 lg = *reinterpret_cast<const float4*>(&s_lg[wv][lane][0]);
        float m  = fmaxf(fmaxf(lg.x, lg.y), fmaxf(lg.z, lg.w));
        float e0 = expf(lg.x - m), e1 = expf(lg.y - m),
              e2 = expf(lg.z - m), e3 = expf(lg.w - m);
        float inv = 1.0f / (e0 + e1 + e2 + e3);
        float p0 = e0 * inv, p1 = e1 * inv, p2 = e2 * inv, p3 = e3 * inv;
        float bp = p0;
        if (p1 > bp) { bp = p1; bi = 1; }
        if (p2 > bp) { bp = p2; bi = 2; }
        if (p3 > bp) { bp = p3; bi = 3; }
        gt = blockIdx.x * 64 + wv * 16 + lane;
        top_prob[gt] = bp;
        rk = atomicAdd(&s_cnt[bi], 1);
        atomicAdd(&s_imp[0], p0); atomicAdd(&s_imp[1], p1);
        atomicAdd(&s_imp[2], p2); atomicAdd(&s_imp[3], p3);
    }
    __syncthreads();
    if (tid < NE) {
        s_base[tid] = atomicAdd(&counts[tid], s_cnt[tid]);  // reserve + count
        atomicAdd(&importance[tid], s_imp[tid]);
    }
    __syncthreads();
    if (lane < 16)
        order[bi * N_TOK + s_base[bi] + rk] = gt;
}

// ---------------------------------------------------------------------------
// Expert FFN v7: round-9 structure (4 quarter-FF passes, 3 blocks/CU) +
// sigmoid-GELU (rcp) + pre-epilogue barrier (cluster out-writes in time).
// ---------------------------------------------------------------------------
__global__ __launch_bounds__(512, 6) void expert_mfma_kernel(
    const float* __restrict__ h,
    const unsigned short* __restrict__ w1p,
    const unsigned short* __restrict__ w2p,
    const float* __restrict__ b1, const float* __restrict__ b2,
    const float* __restrict__ top_prob,
    const int* __restrict__ order, const int* __restrict__ counts,
    const float* __restrict__ importance, float* __restrict__ out)
{
    __shared__ __align__(16) unsigned short sh_h[8 * 4 * 512];   // 32 KB
    __shared__ __align__(16) unsigned short sh_a[4 * 4 * 512];   // 16 KB
    __shared__ int s_tok[MT];

    const int tid = threadIdx.x;

    if (blockIdx.x == N_TOK / MT + NE) {      // lb block
        if (tid == 0) {
            double num = (double)importance[0] * counts[0] +
                         (double)importance[1] * counts[1] +
                         (double)importance[2] * counts[2] +
                         (double)importance[3] * counts[3];
            out[(size_t)N_TOK * HD] =
                (float)((double)NE * num / ((double)N_TOK * (double)N_TOK + 1e-8));
        }
        return;
    }

    int c = blockIdx.x, e;
    for (e = 0; e < NE; ++e) {
        int nch = (counts[e] + MT - 1) / MT;
        if (c < nch) break;
        c -= nch;
    }
    if (e >= NE) return;
    const int cnt  = counts[e];
    const int base = e * N_TOK + c * MT;
    const int nt   = min(MT, cnt - c * MT);

    if (tid < MT) s_tok[tid] = (tid < nt) ? order[base + tid] : -1;
    __syncthreads();

    #pragma unroll
    for (int it = 0; it < 4; ++it) {
        int chunk = tid + it * 512;
        int tr = chunk >> 5, q = chunk & 31;
        int t = s_tok[tr];
        float4 v0 = make_float4(0.f,0.f,0.f,0.f), v1 = v0;
        if (t >= 0) {
            const float* p = &h[(size_t)t * HD + q * 8];
            v0 = *reinterpret_cast<const float4*>(p);
            v1 = *reinterpret_cast<const float4*>(p + 4);
        }
        short8 o;
        o[0] = (short)f2bf(v0.x); o[1] = (short)f2bf(v0.y);
        o[2] = (short)f2bf(v0.z); o[3] = (short)f2bf(v0.w);
        o[4] = (short)f2bf(v1.x); o[5] = (short)f2bf(v1.y);
        o[6] = (short)f2bf(v1.z); o[7] = (short)f2bf(v1.w);
        int ks = q >> 2, kg = q & 3, mi = tr >> 4, row = tr & 15;
        *reinterpret_cast<short8*>(&sh_h[((ks*4 + mi)*64 + kg*16 + row) * 8]) = o;
    }
    __syncthreads();

    const int lane  = tid & 63;
    const int wv    = tid >> 6;       // 0..7
    const int row15 = lane & 15;
    const int kg    = lane >> 4;

    const unsigned short* W1 = w1p + (size_t)e * 8 * 32 * 512;
    const unsigned short* W2 = w2p + (size_t)e * 16 * 16 * 512;

    f32x4 acc2[2][4];
    #pragma unroll
    for (int ni = 0; ni < 2; ++ni) {
        f32x4 bb = *reinterpret_cast<const f32x4*>(&b2[e * HD + wv * 32 + ni * 16 + kg * 4]);
        #pragma unroll
        for (int mi = 0; mi < 4; ++mi) acc2[ni][mi] = bb;
    }

    const int l_w   = wv >> 1;
    const int kg2_w = (wv & 1) * 2 + (kg >> 1);

    #pragma unroll
    for (int p = 0; p < 4; ++p) {
        f32x4 acc1[4];
        {
            f32x4 bb = *reinterpret_cast<const f32x4*>(
                &b1[e * FF + p * 128 + wv * 16 + kg * 4]);
            #pragma unroll
            for (int mi = 0; mi < 4; ++mi) acc1[mi] = bb;
        }
        #pragma unroll
        for (int ks = 0; ks < 8; ++ks) {
            short8 bh[4];
            #pragma unroll
            for (int mi = 0; mi < 4; ++mi)
                bh[mi] = *reinterpret_cast<const short8*>(&sh_h[((ks*4 + mi)*64 + lane) * 8]);
            short8 aw = *reinterpret_cast<const short8*>(
                &W1[(size_t)((ks*32 + p*8 + wv)*64 + lane) * 8]);
            #pragma unroll
            for (int mi = 0; mi < 4; ++mi)
                acc1[mi] = __builtin_amdgcn_mfma_f32_16x16x32_bf16(aw, bh[mi], acc1[mi], 0, 0, 0);
        }
        if (p > 0) __syncthreads();

        #pragma unroll
        for (int mi = 0; mi < 4; ++mi) {
            ushort4 pk;
            pk.x = f2bf(gelu_s(acc1[mi][0]));
            pk.y = f2bf(gelu_s(acc1[mi][1]));
            pk.z = f2bf(gelu_s(acc1[mi][2]));
            pk.w = f2bf(gelu_s(acc1[mi][3]));
            *reinterpret_cast<ushort4*>(
                &sh_a[(((l_w*4 + mi)*64 + kg2_w*16 + row15) * 8 + (kg & 1) * 4)]) = pk;
        }
        __syncthreads();

        #pragma unroll
        for (int l2 = 0; l2 < 4; ++l2) {
            short8 ba[4];
            #pragma unroll
            for (int mi = 0; mi < 4; ++mi)
                ba[mi] = *reinterpret_cast<const short8*>(&sh_a[((l2*4 + mi)*64 + lane) * 8]);
            #pragma unroll
            for (int ni = 0; ni < 2; ++ni) {
                short8 aw = *reinterpret_cast<const short8*>(
                    &W2[(size_t)(((p*4 + l2)*16 + wv*2 + ni)*64 + lane) * 8]);
                #pragma unroll
                for (int mi = 0; mi < 4; ++mi)
                    acc2[ni][mi] = __builtin_amdgcn_mfma_f32_16x16x32_bf16(aw, ba[mi], acc2[ni][mi], 0, 0, 0);
            }
        }
    }

    // cluster the block's out-writes in time (full lines assembled in L2)
    __syncthreads();

    #pragma unroll
    for (int mi = 0; mi < 4; ++mi) {
        int gt = s_tok[mi * 16 + row15];
        if (gt < 0) continue;
        float tp = 0.5f * top_prob[gt];
        #pragma unroll
        for (int ni = 0; ni < 2; ++ni) {
            int nb = wv * 32 + ni * 16 + kg * 4;
            float4 res = *reinterpret_cast<const float4*>(&h[(size_t)gt * HD + nb]);
            float4 o;
            o.x = res.x + tp * acc2[ni][mi][0];
            o.y = res.y + tp * acc2[ni][mi][1];
            o.z = res.z + tp * acc2[ni][mi][2];
            o.w = res.w + tp * acc2[ni][mi][3];
            *reinterpret_cast<float4*>(&out[(size_t)gt * HD + nb]) = o;
        }
    }
}

// ---------------------------------------------------------------------------
extern "C" void kernel_launch(void* const* d_in, const int* in_sizes, int n_in,
                              void* d_out, int out_size, void* d_ws, size_t ws_size,
                              hipStream_t stream)
{
    const float* h        = (const float*)d_in[0];
    const float* tok_emb  = (const float*)d_in[1];
    /* d_in[2] = is_mask: all zeros, unused by the reference math */
    const float* ln_g     = (const float*)d_in[3];
    const float* ln_b     = (const float*)d_in[4];
    const float* geom_w   = (const float*)d_in[5];
    const float* geom_b   = (const float*)d_in[6];
    const float* fuse_w   = (const float*)d_in[7];
    const float* fuse_b   = (const float*)d_in[8];
    const float* router_w = (const float*)d_in[9];
    const float* router_b = (const float*)d_in[10];
    const float* w1       = (const float*)d_in[11];
    const float* b1       = (const float*)d_in[12];
    const float* w2       = (const float*)d_in[13];
    const float* b2       = (const float*)d_in[14];
    float* out = (float*)d_out;

    // workspace layout (4B word units from d_ws)
    int*   counts     = (int*)d_ws;                        // [4]
    float* importance = (float*)d_ws + 4;                  // [4]
    float* top_prob   = (float*)d_ws + 64;                 // [N]
    int*   order      = (int*)d_ws + 64 + N_TOK;           // [4*N] regions
    unsigned short* w1p = (unsigned short*)((int*)d_ws + 64 + 5 * N_TOK); // 1MB
    unsigned short* w2p = w1p + (size_t)NE * FF * HD;                     // 1MB
    _Float16* wg_hi = (_Float16*)(w2p + (size_t)NE * FF * HD);
    _Float16* wg_lo = wg_hi + 8192;
    _Float16* wf_hi = wg_lo + 8192;
    _Float16* wf_lo = wf_hi + 4096;
    _Float16* wr_hi = wf_lo + 4096;
    _Float16* wr_lo = wr_hi + 1024;
    float*    gb2   = (float*)(wr_lo + 1024);              // [32]

    hipMemsetAsync(d_ws, 0, 64 * sizeof(int), stream);

    prep_all_kernel<<<519, 256, 0, stream>>>(
        w1, w2, w1p, w2p,
        geom_w, geom_b, ln_g, ln_b, fuse_w, router_w,
        wg_hi, wg_lo, wf_hi, wf_lo, wr_hi, wr_lo, gb2);

    router3_kernel<<<N_TOK / 64, 256, 0, stream>>>(
        h, tok_emb, wg_hi, wg_lo, wf_hi, wf_lo, wr_hi, wr_lo,
        gb2, fuse_b, router_b, top_prob, order, counts, importance);

    expert_mfma_kernel<<<N_TOK / MT + NE + 1, 512, 0, stream>>>(
        h, w1p, w2p, b1, b2, top_prob, order, counts, importance, out);
}

// Round 12
// 228.433 us; speedup vs baseline: 1.0945x; 1.0945x over previous
//
#include <hip/hip_runtime.h>
#include <hip/hip_bf16.h>
#include <math.h>

#define N_TOK 131072
#define HD    256
#define DS    32
#define DG    32
#define FM    64
#define NE    4
#define FF    512
#define MT    64   // tokens per expert block (8 waves, 512 threads)

typedef short    short8 __attribute__((ext_vector_type(8)));
typedef _Float16 f16x8  __attribute__((ext_vector_type(8)));
typedef float    f32x4  __attribute__((ext_vector_type(4)));

struct F16Pair { _Float16 hi, lo; };

__device__ __forceinline__ float gelu_f(float x) {        // exact erf
    return 0.5f * x * (1.0f + erff(x * 0.70710678118654752f));
}
__device__ __forceinline__ unsigned short f2bf(float x) {
    union { __hip_bfloat16 b; unsigned short u; } cv;
    cv.b = __float2bfloat16(x);
    return cv.u;
}
__device__ __forceinline__ F16Pair split16(float v) {
    F16Pair p;
    p.hi = (_Float16)v;
    p.lo = (_Float16)(v - (float)p.hi);
    return p;
}

// ---------------------------------------------------------------------------
// Prep-tables (7 blocks): router fp16 hi/lo tables + folded gb2 + ws zeroing.
// Runs before router; zeroes counts/importance (replaces hipMemsetAsync).
// ---------------------------------------------------------------------------
__global__ __launch_bounds__(256) void prep_router_kernel(
    const float* __restrict__ geom_w, const float* __restrict__ geom_b,
    const float* __restrict__ ln_g, const float* __restrict__ ln_b,
    const float* __restrict__ fuse_w, const float* __restrict__ router_w,
    _Float16* __restrict__ wg_hi, _Float16* __restrict__ wg_lo,
    _Float16* __restrict__ wf_hi, _Float16* __restrict__ wf_lo,
    _Float16* __restrict__ wr_hi, _Float16* __restrict__ wr_lo,
    float* __restrict__ gb2, int* __restrict__ ws_zero)
{
    const int slot = blockIdx.x * 256 + threadIdx.x;
    const int lane = slot & 63;
    const int kg   = lane >> 4;
    const int row  = lane & 15;
    if (slot < 1024) {
        const int f = slot >> 6, ks = f >> 1, ni = f & 1;
        const int n = ni * 16 + row;
        f16x8 hi, lo;
        #pragma unroll
        for (int j = 0; j < 8; ++j) {
            int k = ks * 32 + kg * 8 + j;
            F16Pair p = split16(ln_g[k] * geom_w[k * DG + n]);
            hi[j] = p.hi; lo[j] = p.lo;
        }
        *reinterpret_cast<f16x8*>(&wg_hi[(size_t)slot * 8]) = hi;
        *reinterpret_cast<f16x8*>(&wg_lo[(size_t)slot * 8]) = lo;
    } else if (slot < 1536) {
        const int s = slot - 1024;
        const int f = s >> 6, ks = f >> 2, ni = f & 3;
        const int n = ni * 16 + row;
        f16x8 hi, lo;
        #pragma unroll
        for (int j = 0; j < 8; ++j) {
            int k = ks * 32 + kg * 8 + j;
            F16Pair p = split16(fuse_w[k * FM + n]);
            hi[j] = p.hi; lo[j] = p.lo;
        }
        *reinterpret_cast<f16x8*>(&wf_hi[(size_t)s * 8]) = hi;
        *reinterpret_cast<f16x8*>(&wf_lo[(size_t)s * 8]) = lo;
    } else if (slot < 1664) {
        const int s = slot - 1536;
        const int ks = s >> 6;
        f16x8 hi, lo;
        #pragma unroll
        for (int j = 0; j < 8; ++j) {
            int k = ks * 32 + kg * 8 + j;
            F16Pair p = split16((row < NE) ? router_w[k * NE + row] : 0.f);
            hi[j] = p.hi; lo[j] = p.lo;
        }
        *reinterpret_cast<f16x8*>(&wr_hi[(size_t)s * 8]) = hi;
        *reinterpret_cast<f16x8*>(&wr_lo[(size_t)s * 8]) = lo;
    } else if (slot < 1696) {
        const int n = slot - 1664;   // 0..31
        float acc = geom_b[n];
        for (int k = 0; k < HD; ++k) acc += ln_b[k] * geom_w[k * DG + n];
        gb2[n] = acc;
    } else if (slot < 1760) {
        ws_zero[slot - 1696] = 0;    // counts[4] + importance[4] + spare
    }
}

// ---------------------------------------------------------------------------
// Router v4: MFMA router (fp16-split 3-term) + fused bucketing + folded
// expert-weight repack (blocks 0..511, after routing work).
// ---------------------------------------------------------------------------
__global__ __launch_bounds__(256) void router4_kernel(
    const float* __restrict__ h, const float* __restrict__ tok_emb,
    const _Float16* __restrict__ wg_hi, const _Float16* __restrict__ wg_lo,
    const _Float16* __restrict__ wf_hi, const _Float16* __restrict__ wf_lo,
    const _Float16* __restrict__ wr_hi, const _Float16* __restrict__ wr_lo,
    const float* __restrict__ gb2, const float* __restrict__ fuse_b,
    const float* __restrict__ router_b,
    const float* __restrict__ w1, const float* __restrict__ w2,
    unsigned short* __restrict__ w1p, unsigned short* __restrict__ w2p,
    float* __restrict__ top_prob, int* __restrict__ order,
    int* __restrict__ counts, float* __restrict__ importance)
{
    __shared__ __align__(16) _Float16 sg_hi[4][16][40], sg_lo[4][16][40];
    __shared__ __align__(16) _Float16 su_hi[4][16][72], su_lo[4][16][72];
    __shared__ __align__(16) float    s_lg[4][16][4];
    __shared__ float s_imp[NE];
    __shared__ int   s_cnt[NE];
    __shared__ int   s_base[NE];

    const int tid  = threadIdx.x;
    const int wv   = tid >> 6;
    const int lane = tid & 63;
    const int kg   = lane >> 4;
    const int row  = lane & 15;
    const int tok  = blockIdx.x * 64 + wv * 16 + row;

    if (tid < NE) { s_imp[tid] = 0.f; s_cnt[tid] = 0; }
    __syncthreads();

    const float* hrow = h + (size_t)tok * HD;
    float s1 = 0.f, s2 = 0.f;
    #pragma unroll
    for (int ks = 0; ks < 8; ++ks) {
        float4 x0 = *reinterpret_cast<const float4*>(hrow + ks * 32 + kg * 8);
        float4 x1 = *reinterpret_cast<const float4*>(hrow + ks * 32 + kg * 8 + 4);
        s1 += (x0.x + x0.y) + (x0.z + x0.w) + (x1.x + x1.y) + (x1.z + x1.w);
        s2 += x0.x*x0.x + x0.y*x0.y + x0.z*x0.z + x0.w*x0.w
            + x1.x*x1.x + x1.y*x1.y + x1.z*x1.z + x1.w*x1.w;
    }
    s1 += __shfl_xor(s1, 16); s1 += __shfl_xor(s1, 32);
    s2 += __shfl_xor(s2, 16); s2 += __shfl_xor(s2, 32);
    const float mu   = s1 * (1.0f / HD);
    const float var  = s2 * (1.0f / HD) - mu * mu;
    const float rstd = rsqrtf(var + 1e-5f);

    f16x8 ahi[8], alo[8];
    #pragma unroll
    for (int ks = 0; ks < 8; ++ks) {
        float4 x0 = *reinterpret_cast<const float4*>(hrow + ks * 32 + kg * 8);
        float4 x1 = *reinterpret_cast<const float4*>(hrow + ks * 32 + kg * 8 + 4);
        float v[8] = {x0.x, x0.y, x0.z, x0.w, x1.x, x1.y, x1.z, x1.w};
        #pragma unroll
        for (int j = 0; j < 8; ++j) {
            F16Pair p = split16((v[j] - mu) * rstd);
            ahi[ks][j] = p.hi; alo[ks][j] = p.lo;
        }
    }

    const f16x8* WGH = reinterpret_cast<const f16x8*>(wg_hi);
    const f16x8* WGL = reinterpret_cast<const f16x8*>(wg_lo);
    f32x4 accg[2];
    #pragma unroll
    for (int ni = 0; ni < 2; ++ni) {
        float bb = gb2[ni * 16 + row];
        accg[ni] = (f32x4){bb, bb, bb, bb};
    }
    #pragma unroll
    for (int ks = 0; ks < 8; ++ks) {
        #pragma unroll
        for (int ni = 0; ni < 2; ++ni) {
            f16x8 bh = WGH[(ks * 2 + ni) * 64 + lane];
            f16x8 bl = WGL[(ks * 2 + ni) * 64 + lane];
            accg[ni] = __builtin_amdgcn_mfma_f32_16x16x32_f16(ahi[ks], bh, accg[ni], 0, 0, 0);
            accg[ni] = __builtin_amdgcn_mfma_f32_16x16x32_f16(alo[ks], bh, accg[ni], 0, 0, 0);
            accg[ni] = __builtin_amdgcn_mfma_f32_16x16x32_f16(ahi[ks], bl, accg[ni], 0, 0, 0);
        }
    }
    #pragma unroll
    for (int ni = 0; ni < 2; ++ni)
        #pragma unroll
        for (int r = 0; r < 4; ++r) {
            F16Pair p = split16(gelu_f(accg[ni][r]));
            sg_hi[wv][kg * 4 + r][ni * 16 + row] = p.hi;
            sg_lo[wv][kg * 4 + r][ni * 16 + row] = p.lo;
        }

    f16x8 a2h[2], a2l[2];
    {
        const float* terow = tok_emb + (size_t)tok * DS;
        float4 x0 = *reinterpret_cast<const float4*>(terow + kg * 8);
        float4 x1 = *reinterpret_cast<const float4*>(terow + kg * 8 + 4);
        float v[8] = {x0.x, x0.y, x0.z, x0.w, x1.x, x1.y, x1.z, x1.w};
        #pragma unroll
        for (int j = 0; j < 8; ++j) {
            F16Pair p = split16(v[j]);
            a2h[0][j] = p.hi; a2l[0][j] = p.lo;
        }
        a2h[1] = *reinterpret_cast<const f16x8*>(&sg_hi[wv][row][kg * 8]);
        a2l[1] = *reinterpret_cast<const f16x8*>(&sg_lo[wv][row][kg * 8]);
    }
    const f16x8* WFH = reinterpret_cast<const f16x8*>(wf_hi);
    const f16x8* WFL = reinterpret_cast<const f16x8*>(wf_lo);
    f32x4 accf[4];
    #pragma unroll
    for (int ni = 0; ni < 4; ++ni) {
        float bb = fuse_b[ni * 16 + row];
        accf[ni] = (f32x4){bb, bb, bb, bb};
    }
    #pragma unroll
    for (int ks = 0; ks < 2; ++ks) {
        #pragma unroll
        for (int ni = 0; ni < 4; ++ni) {
            f16x8 bh = WFH[(ks * 4 + ni) * 64 + lane];
            f16x8 bl = WFL[(ks * 4 + ni) * 64 + lane];
            accf[ni] = __builtin_amdgcn_mfma_f32_16x16x32_f16(a2h[ks], bh, accf[ni], 0, 0, 0);
            accf[ni] = __builtin_amdgcn_mfma_f32_16x16x32_f16(a2l[ks], bh, accf[ni], 0, 0, 0);
            accf[ni] = __builtin_amdgcn_mfma_f32_16x16x32_f16(a2h[ks], bl, accf[ni], 0, 0, 0);
        }
    }
    #pragma unroll
    for (int ni = 0; ni < 4; ++ni)
        #pragma unroll
        for (int r = 0; r < 4; ++r) {
            F16Pair p = split16(gelu_f(accf[ni][r]));
            su_hi[wv][kg * 4 + r][ni * 16 + row] = p.hi;
            su_lo[wv][kg * 4 + r][ni * 16 + row] = p.lo;
        }

    const f16x8* WRH = reinterpret_cast<const f16x8*>(wr_hi);
    const f16x8* WRL = reinterpret_cast<const f16x8*>(wr_lo);
    f32x4 accl = (f32x4){0.f, 0.f, 0.f, 0.f};
    #pragma unroll
    for (int ks = 0; ks < 2; ++ks) {
        f16x8 a3h = *reinterpret_cast<const f16x8*>(&su_hi[wv][row][ks * 32 + kg * 8]);
        f16x8 a3l = *reinterpret_cast<const f16x8*>(&su_lo[wv][row][ks * 32 + kg * 8]);
        f16x8 bh = WRH[ks * 64 + lane];
        f16x8 bl = WRL[ks * 64 + lane];
        accl = __builtin_amdgcn_mfma_f32_16x16x32_f16(a3h, bh, accl, 0, 0, 0);
        accl = __builtin_amdgcn_mfma_f32_16x16x32_f16(a3l, bh, accl, 0, 0, 0);
        accl = __builtin_amdgcn_mfma_f32_16x16x32_f16(a3h, bl, accl, 0, 0, 0);
    }
    if (row < NE) {
        float rb = router_b[row];
        #pragma unroll
        for (int r = 0; r < 4; ++r)
            s_lg[wv][kg * 4 + r][row] = accl[r] + rb;
    }
    __syncthreads();

    int bi = 0, rk = 0, gt = 0;
    if (lane < 16) {
        float4 lg = *reinterpret_cast<const float4*>(&s_lg[wv][lane][0]);
        float m  = fmaxf(fmaxf(lg.x, lg.y), fmaxf(lg.z, lg.w));
        float e0 = expf(lg.x - m), e1 = expf(lg.y - m),
              e2 = expf(lg.z - m), e3 = expf(lg.w - m);
        float inv = 1.0f / (e0 + e1 + e2 + e3);
        float p0 = e0 * inv, p1 = e1 * inv, p2 = e2 * inv, p3 = e3 * inv;
        float bp = p0;
        if (p1 > bp) { bp = p1; bi = 1; }
        if (p2 > bp) { bp = p2; bi = 2; }
        if (p3 > bp) { bp = p3; bi = 3; }
        gt = blockIdx.x * 64 + wv * 16 + lane;
        top_prob[gt] = bp;
        rk = atomicAdd(&s_cnt[bi], 1);
        atomicAdd(&s_imp[0], p0); atomicAdd(&s_imp[1], p1);
        atomicAdd(&s_imp[2], p2); atomicAdd(&s_imp[3], p3);
    }
    __syncthreads();
    if (tid < NE) {
        s_base[tid] = atomicAdd(&counts[tid], s_cnt[tid]);  // reserve + count
        atomicAdd(&importance[tid], s_imp[tid]);
    }
    __syncthreads();
    if (lane < 16)
        order[bi * N_TOK + s_base[bi] + rk] = gt;

    // ---- folded expert-weight repack (consumed by next launch only) ------
    if (blockIdx.x < 512) {
        int t = (blockIdx.x & 255) * 256 + tid;
        const int pl  = t & 63;
        const int pkg = pl >> 4;
        const int prw = pl & 15;
        if (blockIdx.x < 256) {
            const int ni = (t >> 6) & 31;
            const int ks = (t >> 11) & 7;
            const int e  = t >> 14;
            const int n  = ni * 16 + prw;
            const int k0 = ks * 32 + pkg * 8;
            short8 o;
            #pragma unroll
            for (int j = 0; j < 8; ++j)
                o[j] = (short)f2bf(w1[((size_t)e * HD + k0 + j) * FF + n]);
            *reinterpret_cast<short8*>(&w1p[(size_t)(((e*8 + ks)*32 + ni)*64 + pl) * 8]) = o;
        } else {
            const int ni = (t >> 6) & 15;
            const int ks = (t >> 10) & 15;
            const int e  = t >> 14;
            const int n  = ni * 16 + prw;
            const int k0 = ks * 32 + pkg * 8;
            short8 o;
            #pragma unroll
            for (int j = 0; j < 8; ++j)
                o[j] = (short)f2bf(w2[((size_t)e * FF + k0 + j) * HD + n]);
            *reinterpret_cast<short8*>(&w2p[(size_t)(((e*16 + ks)*16 + ni)*64 + pl) * 8]) = o;
        }
    }
}

// ---------------------------------------------------------------------------
// Expert FFN — EXACT round-9 version (verified 137 µs): operand-swapped MFMA,
// 4 quarter-FF passes, 3 blocks/CU, erf-GELU. lb block at end.
// ---------------------------------------------------------------------------
__global__ __launch_bounds__(512, 6) void expert_mfma_kernel(
    const float* __restrict__ h,
    const unsigned short* __restrict__ w1p,
    const unsigned short* __restrict__ w2p,
    const float* __restrict__ b1, const float* __restrict__ b2,
    const float* __restrict__ top_prob,
    const int* __restrict__ order, const int* __restrict__ counts,
    const float* __restrict__ importance, float* __restrict__ out)
{
    __shared__ __align__(16) unsigned short sh_h[8 * 4 * 512];   // 32 KB
    __shared__ __align__(16) unsigned short sh_a[4 * 4 * 512];   // 16 KB
    __shared__ int s_tok[MT];

    const int tid = threadIdx.x;

    if (blockIdx.x == N_TOK / MT + NE) {      // lb block
        if (tid == 0) {
            double num = (double)importance[0] * counts[0] +
                         (double)importance[1] * counts[1] +
                         (double)importance[2] * counts[2] +
                         (double)importance[3] * counts[3];
            out[(size_t)N_TOK * HD] =
                (float)((double)NE * num / ((double)N_TOK * (double)N_TOK + 1e-8));
        }
        return;
    }

    int c = blockIdx.x, e;
    for (e = 0; e < NE; ++e) {
        int nch = (counts[e] + MT - 1) / MT;
        if (c < nch) break;
        c -= nch;
    }
    if (e >= NE) return;
    const int cnt  = counts[e];
    const int base = e * N_TOK + c * MT;
    const int nt   = min(MT, cnt - c * MT);

    if (tid < MT) s_tok[tid] = (tid < nt) ? order[base + tid] : -1;
    __syncthreads();

    #pragma unroll
    for (int it = 0; it < 4; ++it) {
        int chunk = tid + it * 512;
        int tr = chunk >> 5, q = chunk & 31;
        int t = s_tok[tr];
        float4 v0 = make_float4(0.f,0.f,0.f,0.f), v1 = v0;
        if (t >= 0) {
            const float* p = &h[(size_t)t * HD + q * 8];
            v0 = *reinterpret_cast<const float4*>(p);
            v1 = *reinterpret_cast<const float4*>(p + 4);
        }
        short8 o;
        o[0] = (short)f2bf(v0.x); o[1] = (short)f2bf(v0.y);
        o[2] = (short)f2bf(v0.z); o[3] = (short)f2bf(v0.w);
        o[4] = (short)f2bf(v1.x); o[5] = (short)f2bf(v1.y);
        o[6] = (short)f2bf(v1.z); o[7] = (short)f2bf(v1.w);
        int ks = q >> 2, kg = q & 3, mi = tr >> 4, row = tr & 15;
        *reinterpret_cast<short8*>(&sh_h[((ks*4 + mi)*64 + kg*16 + row) * 8]) = o;
    }
    __syncthreads();

    const int lane  = tid & 63;
    const int wv    = tid >> 6;       // 0..7
    const int row15 = lane & 15;
    const int kg    = lane >> 4;

    const unsigned short* W1 = w1p + (size_t)e * 8 * 32 * 512;
    const unsigned short* W2 = w2p + (size_t)e * 16 * 16 * 512;

    f32x4 acc2[2][4];
    #pragma unroll
    for (int ni = 0; ni < 2; ++ni) {
        f32x4 bb = *reinterpret_cast<const f32x4*>(&b2[e * HD + wv * 32 + ni * 16 + kg * 4]);
        #pragma unroll
        for (int mi = 0; mi < 4; ++mi) acc2[ni][mi] = bb;
    }

    const int l_w   = wv >> 1;
    const int kg2_w = (wv & 1) * 2 + (kg >> 1);

    #pragma unroll
    for (int p = 0; p < 4; ++p) {
        f32x4 acc1[4];
        {
            f32x4 bb = *reinterpret_cast<const f32x4*>(
                &b1[e * FF + p * 128 + wv * 16 + kg * 4]);
            #pragma unroll
            for (int mi = 0; mi < 4; ++mi) acc1[mi] = bb;
        }
        #pragma unroll
        for (int ks = 0; ks < 8; ++ks) {
            short8 bh[4];
            #pragma unroll
            for (int mi = 0; mi < 4; ++mi)
                bh[mi] = *reinterpret_cast<const short8*>(&sh_h[((ks*4 + mi)*64 + lane) * 8]);
            short8 aw = *reinterpret_cast<const short8*>(
                &W1[(size_t)((ks*32 + p*8 + wv)*64 + lane) * 8]);
            #pragma unroll
            for (int mi = 0; mi < 4; ++mi)
                acc1[mi] = __builtin_amdgcn_mfma_f32_16x16x32_bf16(aw, bh[mi], acc1[mi], 0, 0, 0);
        }
        if (p > 0) __syncthreads();    // pass p-1's sh_a reads complete

        #pragma unroll
        for (int mi = 0; mi < 4; ++mi) {
            ushort4 pk;
            pk.x = f2bf(gelu_f(acc1[mi][0]));
            pk.y = f2bf(gelu_f(acc1[mi][1]));
            pk.z = f2bf(gelu_f(acc1[mi][2]));
            pk.w = f2bf(gelu_f(acc1[mi][3]));
            *reinterpret_cast<ushort4*>(
                &sh_a[(((l_w*4 + mi)*64 + kg2_w*16 + row15) * 8 + (kg & 1) * 4)]) = pk;
        }
        __syncthreads();

        #pragma unroll
        for (int l2 = 0; l2 < 4; ++l2) {
            short8 ba[4];
            #pragma unroll
            for (int mi = 0; mi < 4; ++mi)
                ba[mi] = *reinterpret_cast<const short8*>(&sh_a[((l2*4 + mi)*64 + lane) * 8]);
            #pragma unroll
            for (int ni = 0; ni < 2; ++ni) {
                short8 aw = *reinterpret_cast<const short8*>(
                    &W2[(size_t)(((p*4 + l2)*16 + wv*2 + ni)*64 + lane) * 8]);
                #pragma unroll
                for (int mi = 0; mi < 4; ++mi)
                    acc2[ni][mi] = __builtin_amdgcn_mfma_f32_16x16x32_bf16(aw, ba[mi], acc2[ni][mi], 0, 0, 0);
            }
        }
    }

    #pragma unroll
    for (int mi = 0; mi < 4; ++mi) {
        int gt = s_tok[mi * 16 + row15];
        if (gt < 0) continue;
        float tp = 0.5f * top_prob[gt];
        #pragma unroll
        for (int ni = 0; ni < 2; ++ni) {
            int nb = wv * 32 + ni * 16 + kg * 4;
            float4 res = *reinterpret_cast<const float4*>(&h[(size_t)gt * HD + nb]);
            float4 o;
            o.x = res.x + tp * acc2[ni][mi][0];
            o.y = res.y + tp * acc2[ni][mi][1];
            o.z = res.z + tp * acc2[ni][mi][2];
            o.w = res.w + tp * acc2[ni][mi][3];
            *reinterpret_cast<float4*>(&out[(size_t)gt * HD + nb]) = o;
        }
    }
}

// ---------------------------------------------------------------------------
extern "C" void kernel_launch(void* const* d_in, const int* in_sizes, int n_in,
                              void* d_out, int out_size, void* d_ws, size_t ws_size,
                              hipStream_t stream)
{
    const float* h        = (const float*)d_in[0];
    const float* tok_emb  = (const float*)d_in[1];
    /* d_in[2] = is_mask: all zeros, unused by the reference math */
    const float* ln_g     = (const float*)d_in[3];
    const float* ln_b     = (const float*)d_in[4];
    const float* geom_w   = (const float*)d_in[5];
    const float* geom_b   = (const float*)d_in[6];
    const float* fuse_w   = (const float*)d_in[7];
    const float* fuse_b   = (const float*)d_in[8];
    const float* router_w = (const float*)d_in[9];
    const float* router_b = (const float*)d_in[10];
    const float* w1       = (const float*)d_in[11];
    const float* b1       = (const float*)d_in[12];
    const float* w2       = (const float*)d_in[13];
    const float* b2       = (const float*)d_in[14];
    float* out = (float*)d_out;

    // workspace layout (4B word units from d_ws)
    int*   counts     = (int*)d_ws;                        // [4]
    float* importance = (float*)d_ws + 4;                  // [4]
    float* top_prob   = (float*)d_ws + 64;                 // [N]
    int*   order      = (int*)d_ws + 64 + N_TOK;           // [4*N] regions
    unsigned short* w1p = (unsigned short*)((int*)d_ws + 64 + 5 * N_TOK); // 1MB
    unsigned short* w2p = w1p + (size_t)NE * FF * HD;                     // 1MB
    _Float16* wg_hi = (_Float16*)(w2p + (size_t)NE * FF * HD);
    _Float16* wg_lo = wg_hi + 8192;
    _Float16* wf_hi = wg_lo + 8192;
    _Float16* wf_lo = wf_hi + 4096;
    _Float16* wr_hi = wf_lo + 4096;
    _Float16* wr_lo = wr_hi + 1024;
    float*    gb2   = (float*)(wr_lo + 1024);              // [32]

    prep_router_kernel<<<7, 256, 0, stream>>>(
        geom_w, geom_b, ln_g, ln_b, fuse_w, router_w,
        wg_hi, wg_lo, wf_hi, wf_lo, wr_hi, wr_lo, gb2, (int*)d_ws);

    router4_kernel<<<N_TOK / 64, 256, 0, stream>>>(
        h, tok_emb, wg_hi, wg_lo, wf_hi, wf_lo, wr_hi, wr_lo,
        gb2, fuse_b, router_b, w1, w2, w1p, w2p,
        top_prob, order, counts, importance);

    expert_mfma_kernel<<<N_TOK / MT + NE + 1, 512, 0, stream>>>(
        h, w1p, w2p, b1, b2, top_prob, order, counts, importance, out);
}

// Round 13
// 208.233 us; speedup vs baseline: 1.2006x; 1.0970x over previous
//
#include <hip/hip_runtime.h>
#include <hip/hip_bf16.h>
#include <math.h>

#define N_TOK 131072
#define HD    256
#define DS    32
#define DG    32
#define FM    64
#define NE    4
#define FF    512
#define MT    64   // tokens per expert block (8 waves, 512 threads)

typedef short    short8 __attribute__((ext_vector_type(8)));
typedef _Float16 f16x8  __attribute__((ext_vector_type(8)));
typedef float    f32x4  __attribute__((ext_vector_type(4)));

struct F16Pair { _Float16 hi, lo; };

__device__ __forceinline__ float gelu_f(float x) {        // exact erf
    return 0.5f * x * (1.0f + erff(x * 0.70710678118654752f));
}
__device__ __forceinline__ unsigned short f2bf(float x) {
    union { __hip_bfloat16 b; unsigned short u; } cv;
    cv.b = __float2bfloat16(x);
    return cv.u;
}
__device__ __forceinline__ float bf2f(unsigned short u) {
    union { unsigned int i; float f; } cv;
    cv.i = (unsigned int)u << 16;
    return cv.f;
}
__device__ __forceinline__ F16Pair split16(float v) {
    F16Pair p;
    p.hi = (_Float16)v;
    p.lo = (_Float16)(v - (float)p.hi);
    return p;
}

// ---------------------------------------------------------------------------
// Prep-tables (7 blocks): router fp16 hi/lo tables + folded gb2 + ws zeroing.
// ---------------------------------------------------------------------------
__global__ __launch_bounds__(256) void prep_router_kernel(
    const float* __restrict__ geom_w, const float* __restrict__ geom_b,
    const float* __restrict__ ln_g, const float* __restrict__ ln_b,
    const float* __restrict__ fuse_w, const float* __restrict__ router_w,
    _Float16* __restrict__ wg_hi, _Float16* __restrict__ wg_lo,
    _Float16* __restrict__ wf_hi, _Float16* __restrict__ wf_lo,
    _Float16* __restrict__ wr_hi, _Float16* __restrict__ wr_lo,
    float* __restrict__ gb2, int* __restrict__ ws_zero)
{
    const int slot = blockIdx.x * 256 + threadIdx.x;
    const int lane = slot & 63;
    const int kg   = lane >> 4;
    const int row  = lane & 15;
    if (slot < 1024) {
        const int f = slot >> 6, ks = f >> 1, ni = f & 1;
        const int n = ni * 16 + row;
        f16x8 hi, lo;
        #pragma unroll
        for (int j = 0; j < 8; ++j) {
            int k = ks * 32 + kg * 8 + j;
            F16Pair p = split16(ln_g[k] * geom_w[k * DG + n]);
            hi[j] = p.hi; lo[j] = p.lo;
        }
        *reinterpret_cast<f16x8*>(&wg_hi[(size_t)slot * 8]) = hi;
        *reinterpret_cast<f16x8*>(&wg_lo[(size_t)slot * 8]) = lo;
    } else if (slot < 1536) {
        const int s = slot - 1024;
        const int f = s >> 6, ks = f >> 2, ni = f & 3;
        const int n = ni * 16 + row;
        f16x8 hi, lo;
        #pragma unroll
        for (int j = 0; j < 8; ++j) {
            int k = ks * 32 + kg * 8 + j;
            F16Pair p = split16(fuse_w[k * FM + n]);
            hi[j] = p.hi; lo[j] = p.lo;
        }
        *reinterpret_cast<f16x8*>(&wf_hi[(size_t)s * 8]) = hi;
        *reinterpret_cast<f16x8*>(&wf_lo[(size_t)s * 8]) = lo;
    } else if (slot < 1664) {
        const int s = slot - 1536;
        const int ks = s >> 6;
        f16x8 hi, lo;
        #pragma unroll
        for (int j = 0; j < 8; ++j) {
            int k = ks * 32 + kg * 8 + j;
            F16Pair p = split16((row < NE) ? router_w[k * NE + row] : 0.f);
            hi[j] = p.hi; lo[j] = p.lo;
        }
        *reinterpret_cast<f16x8*>(&wr_hi[(size_t)s * 8]) = hi;
        *reinterpret_cast<f16x8*>(&wr_lo[(size_t)s * 8]) = lo;
    } else if (slot < 1696) {
        const int n = slot - 1664;   // 0..31
        float acc = geom_b[n];
        for (int k = 0; k < HD; ++k) acc += ln_b[k] * geom_w[k * DG + n];
        gb2[n] = acc;
    } else if (slot < 1760) {
        ws_zero[slot - 1696] = 0;    // counts[4] + importance[4] + spare
    }
}

// ---------------------------------------------------------------------------
// Router v5: single-pass h (registers), MFMA fp16-split 3-term, fused
// bucketing, folded expert-weight repack (blocks 0..511).
// ---------------------------------------------------------------------------
__global__ __launch_bounds__(256) void router5_kernel(
    const float* __restrict__ h, const float* __restrict__ tok_emb,
    const _Float16* __restrict__ wg_hi, const _Float16* __restrict__ wg_lo,
    const _Float16* __restrict__ wf_hi, const _Float16* __restrict__ wf_lo,
    const _Float16* __restrict__ wr_hi, const _Float16* __restrict__ wr_lo,
    const float* __restrict__ gb2, const float* __restrict__ fuse_b,
    const float* __restrict__ router_b,
    const float* __restrict__ w1, const float* __restrict__ w2,
    unsigned short* __restrict__ w1p, unsigned short* __restrict__ w2p,
    float* __restrict__ top_prob, int* __restrict__ order,
    int* __restrict__ counts, float* __restrict__ importance)
{
    __shared__ __align__(16) _Float16 sg_hi[4][16][40], sg_lo[4][16][40];
    __shared__ __align__(16) _Float16 su_hi[4][16][72], su_lo[4][16][72];
    __shared__ __align__(16) float    s_lg[4][16][4];
    __shared__ float s_imp[NE];
    __shared__ int   s_cnt[NE];
    __shared__ int   s_base[NE];

    const int tid  = threadIdx.x;
    const int wv   = tid >> 6;
    const int lane = tid & 63;
    const int kg   = lane >> 4;
    const int row  = lane & 15;
    const int tok  = blockIdx.x * 64 + wv * 16 + row;

    if (tid < NE) { s_imp[tid] = 0.f; s_cnt[tid] = 0; }
    __syncthreads();

    // ---- single pass: load h into registers, stats, then split ----
    const float* hrow = h + (size_t)tok * HD;
    f32x4 v0[8], v1[8];
    float s1 = 0.f, s2 = 0.f;
    #pragma unroll
    for (int ks = 0; ks < 8; ++ks) {
        v0[ks] = *reinterpret_cast<const f32x4*>(hrow + ks * 32 + kg * 8);
        v1[ks] = *reinterpret_cast<const f32x4*>(hrow + ks * 32 + kg * 8 + 4);
        s1 += (v0[ks][0] + v0[ks][1]) + (v0[ks][2] + v0[ks][3])
            + (v1[ks][0] + v1[ks][1]) + (v1[ks][2] + v1[ks][3]);
        s2 += v0[ks][0]*v0[ks][0] + v0[ks][1]*v0[ks][1]
            + v0[ks][2]*v0[ks][2] + v0[ks][3]*v0[ks][3]
            + v1[ks][0]*v1[ks][0] + v1[ks][1]*v1[ks][1]
            + v1[ks][2]*v1[ks][2] + v1[ks][3]*v1[ks][3];
    }
    s1 += __shfl_xor(s1, 16); s1 += __shfl_xor(s1, 32);
    s2 += __shfl_xor(s2, 16); s2 += __shfl_xor(s2, 32);
    const float mu   = s1 * (1.0f / HD);
    const float var  = s2 * (1.0f / HD) - mu * mu;
    const float rstd = rsqrtf(var + 1e-5f);

    f16x8 ahi[8], alo[8];
    #pragma unroll
    for (int ks = 0; ks < 8; ++ks) {
        #pragma unroll
        for (int j = 0; j < 4; ++j) {
            F16Pair p = split16((v0[ks][j] - mu) * rstd);
            ahi[ks][j] = p.hi; alo[ks][j] = p.lo;
            F16Pair q = split16((v1[ks][j] - mu) * rstd);
            ahi[ks][4 + j] = q.hi; alo[ks][4 + j] = q.lo;
        }
    }

    const f16x8* WGH = reinterpret_cast<const f16x8*>(wg_hi);
    const f16x8* WGL = reinterpret_cast<const f16x8*>(wg_lo);
    f32x4 accg[2];
    #pragma unroll
    for (int ni = 0; ni < 2; ++ni) {
        float bb = gb2[ni * 16 + row];
        accg[ni] = (f32x4){bb, bb, bb, bb};
    }
    #pragma unroll
    for (int ks = 0; ks < 8; ++ks) {
        #pragma unroll
        for (int ni = 0; ni < 2; ++ni) {
            f16x8 bh = WGH[(ks * 2 + ni) * 64 + lane];
            f16x8 bl = WGL[(ks * 2 + ni) * 64 + lane];
            accg[ni] = __builtin_amdgcn_mfma_f32_16x16x32_f16(ahi[ks], bh, accg[ni], 0, 0, 0);
            accg[ni] = __builtin_amdgcn_mfma_f32_16x16x32_f16(alo[ks], bh, accg[ni], 0, 0, 0);
            accg[ni] = __builtin_amdgcn_mfma_f32_16x16x32_f16(ahi[ks], bl, accg[ni], 0, 0, 0);
        }
    }
    #pragma unroll
    for (int ni = 0; ni < 2; ++ni)
        #pragma unroll
        for (int r = 0; r < 4; ++r) {
            F16Pair p = split16(gelu_f(accg[ni][r]));
            sg_hi[wv][kg * 4 + r][ni * 16 + row] = p.hi;
            sg_lo[wv][kg * 4 + r][ni * 16 + row] = p.lo;
        }

    f16x8 a2h[2], a2l[2];
    {
        const float* terow = tok_emb + (size_t)tok * DS;
        float4 x0 = *reinterpret_cast<const float4*>(terow + kg * 8);
        float4 x1 = *reinterpret_cast<const float4*>(terow + kg * 8 + 4);
        float v[8] = {x0.x, x0.y, x0.z, x0.w, x1.x, x1.y, x1.z, x1.w};
        #pragma unroll
        for (int j = 0; j < 8; ++j) {
            F16Pair p = split16(v[j]);
            a2h[0][j] = p.hi; a2l[0][j] = p.lo;
        }
        a2h[1] = *reinterpret_cast<const f16x8*>(&sg_hi[wv][row][kg * 8]);
        a2l[1] = *reinterpret_cast<const f16x8*>(&sg_lo[wv][row][kg * 8]);
    }
    const f16x8* WFH = reinterpret_cast<const f16x8*>(wf_hi);
    const f16x8* WFL = reinterpret_cast<const f16x8*>(wf_lo);
    f32x4 accf[4];
    #pragma unroll
    for (int ni = 0; ni < 4; ++ni) {
        float bb = fuse_b[ni * 16 + row];
        accf[ni] = (f32x4){bb, bb, bb, bb};
    }
    #pragma unroll
    for (int ks = 0; ks < 2; ++ks) {
        #pragma unroll
        for (int ni = 0; ni < 4; ++ni) {
            f16x8 bh = WFH[(ks * 4 + ni) * 64 + lane];
            f16x8 bl = WFL[(ks * 4 + ni) * 64 + lane];
            accf[ni] = __builtin_amdgcn_mfma_f32_16x16x32_f16(a2h[ks], bh, accf[ni], 0, 0, 0);
            accf[ni] = __builtin_amdgcn_mfma_f32_16x16x32_f16(a2l[ks], bh, accf[ni], 0, 0, 0);
            accf[ni] = __builtin_amdgcn_mfma_f32_16x16x32_f16(a2h[ks], bl, accf[ni], 0, 0, 0);
        }
    }
    #pragma unroll
    for (int ni = 0; ni < 4; ++ni)
        #pragma unroll
        for (int r = 0; r < 4; ++r) {
            F16Pair p = split16(gelu_f(accf[ni][r]));
            su_hi[wv][kg * 4 + r][ni * 16 + row] = p.hi;
            su_lo[wv][kg * 4 + r][ni * 16 + row] = p.lo;
        }

    const f16x8* WRH = reinterpret_cast<const f16x8*>(wr_hi);
    const f16x8* WRL = reinterpret_cast<const f16x8*>(wr_lo);
    f32x4 accl = (f32x4){0.f, 0.f, 0.f, 0.f};
    #pragma unroll
    for (int ks = 0; ks < 2; ++ks) {
        f16x8 a3h = *reinterpret_cast<const f16x8*>(&su_hi[wv][row][ks * 32 + kg * 8]);
        f16x8 a3l = *reinterpret_cast<const f16x8*>(&su_lo[wv][row][ks * 32 + kg * 8]);
        f16x8 bh = WRH[ks * 64 + lane];
        f16x8 bl = WRL[ks * 64 + lane];
        accl = __builtin_amdgcn_mfma_f32_16x16x32_f16(a3h, bh, accl, 0, 0, 0);
        accl = __builtin_amdgcn_mfma_f32_16x16x32_f16(a3l, bh, accl, 0, 0, 0);
        accl = __builtin_amdgcn_mfma_f32_16x16x32_f16(a3h, bl, accl, 0, 0, 0);
    }
    if (row < NE) {
        float rb = router_b[row];
        #pragma unroll
        for (int r = 0; r < 4; ++r)
            s_lg[wv][kg * 4 + r][row] = accl[r] + rb;
    }
    __syncthreads();

    int bi = 0, rk = 0, gt = 0;
    if (lane < 16) {
        float4 lg = *reinterpret_cast<const float4*>(&s_lg[wv][lane][0]);
        float m  = fmaxf(fmaxf(lg.x, lg.y), fmaxf(lg.z, lg.w));
        float e0 = expf(lg.x - m), e1 = expf(lg.y - m),
              e2 = expf(lg.z - m), e3 = expf(lg.w - m);
        float inv = 1.0f / (e0 + e1 + e2 + e3);
        float p0 = e0 * inv, p1 = e1 * inv, p2 = e2 * inv, p3 = e3 * inv;
        float bp = p0;
        if (p1 > bp) { bp = p1; bi = 1; }
        if (p2 > bp) { bp = p2; bi = 2; }
        if (p3 > bp) { bp = p3; bi = 3; }
        gt = blockIdx.x * 64 + wv * 16 + lane;
        top_prob[gt] = bp;
        rk = atomicAdd(&s_cnt[bi], 1);
        atomicAdd(&s_imp[0], p0); atomicAdd(&s_imp[1], p1);
        atomicAdd(&s_imp[2], p2); atomicAdd(&s_imp[3], p3);
    }
    __syncthreads();
    if (tid < NE) {
        s_base[tid] = atomicAdd(&counts[tid], s_cnt[tid]);  // reserve + count
        atomicAdd(&importance[tid], s_imp[tid]);
    }
    __syncthreads();
    if (lane < 16)
        order[bi * N_TOK + s_base[bi] + rk] = gt;

    // ---- folded expert-weight repack (consumed by next launch only) ------
    if (blockIdx.x < 512) {
        int t = (blockIdx.x & 255) * 256 + tid;
        const int pl  = t & 63;
        const int pkg = pl >> 4;
        const int prw = pl & 15;
        if (blockIdx.x < 256) {
            const int ni = (t >> 6) & 31;
            const int ks = (t >> 11) & 7;
            const int e  = t >> 14;
            const int n  = ni * 16 + prw;
            const int k0 = ks * 32 + pkg * 8;
            short8 o;
            #pragma unroll
            for (int j = 0; j < 8; ++j)
                o[j] = (short)f2bf(w1[((size_t)e * HD + k0 + j) * FF + n]);
            *reinterpret_cast<short8*>(&w1p[(size_t)(((e*8 + ks)*32 + ni)*64 + pl) * 8]) = o;
        } else {
            const int ni = (t >> 6) & 15;
            const int ks = (t >> 10) & 15;
            const int e  = t >> 14;
            const int n  = ni * 16 + prw;
            const int k0 = ks * 32 + pkg * 8;
            short8 o;
            #pragma unroll
            for (int j = 0; j < 8; ++j)
                o[j] = (short)f2bf(w2[((size_t)e * FF + k0 + j) * HD + n]);
            *reinterpret_cast<short8*>(&w2p[(size_t)(((e*16 + ks)*16 + ni)*64 + pl) * 8]) = o;
        }
    }
}

// ---------------------------------------------------------------------------
// Expert FFN v8: round-9 structure (4 quarter-FF passes, 3 blocks/CU,
// erf-GELU) + residual taken from sh_h (bf16) — no epilogue h re-read.
// ---------------------------------------------------------------------------
__global__ __launch_bounds__(512, 6) void expert_mfma_kernel(
    const float* __restrict__ h,
    const unsigned short* __restrict__ w1p,
    const unsigned short* __restrict__ w2p,
    const float* __restrict__ b1, const float* __restrict__ b2,
    const float* __restrict__ top_prob,
    const int* __restrict__ order, const int* __restrict__ counts,
    const float* __restrict__ importance, float* __restrict__ out)
{
    __shared__ __align__(16) unsigned short sh_h[8 * 4 * 512];   // 32 KB
    __shared__ __align__(16) unsigned short sh_a[4 * 4 * 512];   // 16 KB
    __shared__ int s_tok[MT];

    const int tid = threadIdx.x;

    if (blockIdx.x == N_TOK / MT + NE) {      // lb block
        if (tid == 0) {
            double num = (double)importance[0] * counts[0] +
                         (double)importance[1] * counts[1] +
                         (double)importance[2] * counts[2] +
                         (double)importance[3] * counts[3];
            out[(size_t)N_TOK * HD] =
                (float)((double)NE * num / ((double)N_TOK * (double)N_TOK + 1e-8));
        }
        return;
    }

    int c = blockIdx.x, e;
    for (e = 0; e < NE; ++e) {
        int nch = (counts[e] + MT - 1) / MT;
        if (c < nch) break;
        c -= nch;
    }
    if (e >= NE) return;
    const int cnt  = counts[e];
    const int base = e * N_TOK + c * MT;
    const int nt   = min(MT, cnt - c * MT);

    if (tid < MT) s_tok[tid] = (tid < nt) ? order[base + tid] : -1;
    __syncthreads();

    #pragma unroll
    for (int it = 0; it < 4; ++it) {
        int chunk = tid + it * 512;
        int tr = chunk >> 5, q = chunk & 31;
        int t = s_tok[tr];
        float4 v0 = make_float4(0.f,0.f,0.f,0.f), v1 = v0;
        if (t >= 0) {
            const float* p = &h[(size_t)t * HD + q * 8];
            v0 = *reinterpret_cast<const float4*>(p);
            v1 = *reinterpret_cast<const float4*>(p + 4);
        }
        short8 o;
        o[0] = (short)f2bf(v0.x); o[1] = (short)f2bf(v0.y);
        o[2] = (short)f2bf(v0.z); o[3] = (short)f2bf(v0.w);
        o[4] = (short)f2bf(v1.x); o[5] = (short)f2bf(v1.y);
        o[6] = (short)f2bf(v1.z); o[7] = (short)f2bf(v1.w);
        int ks = q >> 2, kg = q & 3, mi = tr >> 4, row = tr & 15;
        *reinterpret_cast<short8*>(&sh_h[((ks*4 + mi)*64 + kg*16 + row) * 8]) = o;
    }
    __syncthreads();

    const int lane  = tid & 63;
    const int wv    = tid >> 6;       // 0..7
    const int row15 = lane & 15;
    const int kg    = lane >> 4;

    const unsigned short* W1 = w1p + (size_t)e * 8 * 32 * 512;
    const unsigned short* W2 = w2p + (size_t)e * 16 * 16 * 512;

    f32x4 acc2[2][4];
    #pragma unroll
    for (int ni = 0; ni < 2; ++ni) {
        f32x4 bb = *reinterpret_cast<const f32x4*>(&b2[e * HD + wv * 32 + ni * 16 + kg * 4]);
        #pragma unroll
        for (int mi = 0; mi < 4; ++mi) acc2[ni][mi] = bb;
    }

    const int l_w   = wv >> 1;
    const int kg2_w = (wv & 1) * 2 + (kg >> 1);

    #pragma unroll
    for (int p = 0; p < 4; ++p) {
        f32x4 acc1[4];
        {
            f32x4 bb = *reinterpret_cast<const f32x4*>(
                &b1[e * FF + p * 128 + wv * 16 + kg * 4]);
            #pragma unroll
            for (int mi = 0; mi < 4; ++mi) acc1[mi] = bb;
        }
        #pragma unroll
        for (int ks = 0; ks < 8; ++ks) {
            short8 bh[4];
            #pragma unroll
            for (int mi = 0; mi < 4; ++mi)
                bh[mi] = *reinterpret_cast<const short8*>(&sh_h[((ks*4 + mi)*64 + lane) * 8]);
            short8 aw = *reinterpret_cast<const short8*>(
                &W1[(size_t)((ks*32 + p*8 + wv)*64 + lane) * 8]);
            #pragma unroll
            for (int mi = 0; mi < 4; ++mi)
                acc1[mi] = __builtin_amdgcn_mfma_f32_16x16x32_bf16(aw, bh[mi], acc1[mi], 0, 0, 0);
        }
        if (p > 0) __syncthreads();    // pass p-1's sh_a reads complete

        #pragma unroll
        for (int mi = 0; mi < 4; ++mi) {
            ushort4 pk;
            pk.x = f2bf(gelu_f(acc1[mi][0]));
            pk.y = f2bf(gelu_f(acc1[mi][1]));
            pk.z = f2bf(gelu_f(acc1[mi][2]));
            pk.w = f2bf(gelu_f(acc1[mi][3]));
            *reinterpret_cast<ushort4*>(
                &sh_a[(((l_w*4 + mi)*64 + kg2_w*16 + row15) * 8 + (kg & 1) * 4)]) = pk;
        }
        __syncthreads();

        #pragma unroll
        for (int l2 = 0; l2 < 4; ++l2) {
            short8 ba[4];
            #pragma unroll
            for (int mi = 0; mi < 4; ++mi)
                ba[mi] = *reinterpret_cast<const short8*>(&sh_a[((l2*4 + mi)*64 + lane) * 8]);
            #pragma unroll
            for (int ni = 0; ni < 2; ++ni) {
                short8 aw = *reinterpret_cast<const short8*>(
                    &W2[(size_t)(((p*4 + l2)*16 + wv*2 + ni)*64 + lane) * 8]);
                #pragma unroll
                for (int mi = 0; mi < 4; ++mi)
                    acc2[ni][mi] = __builtin_amdgcn_mfma_f32_16x16x32_bf16(aw, ba[mi], acc2[ni][mi], 0, 0, 0);
            }
        }
    }

    // epilogue: residual from sh_h (bf16) — no global h re-read
    #pragma unroll
    for (int mi = 0; mi < 4; ++mi) {
        int gt = s_tok[mi * 16 + row15];
        if (gt < 0) continue;
        float tp = 0.5f * top_prob[gt];
        #pragma unroll
        for (int ni = 0; ni < 2; ++ni) {
            int nb = wv * 32 + ni * 16 + kg * 4;
            ushort4 rb = *reinterpret_cast<const ushort4*>(
                &sh_h[((wv*4 + mi)*64 + (ni*2 + (kg >> 1))*16 + row15) * 8 + (kg & 1) * 4]);
            float4 o;
            o.x = bf2f(rb.x) + tp * acc2[ni][mi][0];
            o.y = bf2f(rb.y) + tp * acc2[ni][mi][1];
            o.z = bf2f(rb.z) + tp * acc2[ni][mi][2];
            o.w = bf2f(rb.w) + tp * acc2[ni][mi][3];
            *reinterpret_cast<float4*>(&out[(size_t)gt * HD + nb]) = o;
        }
    }
}

// ---------------------------------------------------------------------------
extern "C" void kernel_launch(void* const* d_in, const int* in_sizes, int n_in,
                              void* d_out, int out_size, void* d_ws, size_t ws_size,
                              hipStream_t stream)
{
    const float* h        = (const float*)d_in[0];
    const float* tok_emb  = (const float*)d_in[1];
    /* d_in[2] = is_mask: all zeros, unused by the reference math */
    const float* ln_g     = (const float*)d_in[3];
    const float* ln_b     = (const float*)d_in[4];
    const float* geom_w   = (const float*)d_in[5];
    const float* geom_b   = (const float*)d_in[6];
    const float* fuse_w   = (const float*)d_in[7];
    const float* fuse_b   = (const float*)d_in[8];
    const float* router_w = (const float*)d_in[9];
    const float* router_b = (const float*)d_in[10];
    const float* w1       = (const float*)d_in[11];
    const float* b1       = (const float*)d_in[12];
    const float* w2       = (const float*)d_in[13];
    const float* b2       = (const float*)d_in[14];
    float* out = (float*)d_out;

    // workspace layout (4B word units from d_ws)
    int*   counts     = (int*)d_ws;                        // [4]
    float* importance = (float*)d_ws + 4;                  // [4]
    float* top_prob   = (float*)d_ws + 64;                 // [N]
    int*   order      = (int*)d_ws + 64 + N_TOK;           // [4*N] regions
    unsigned short* w1p = (unsigned short*)((int*)d_ws + 64 + 5 * N_TOK); // 1MB
    unsigned short* w2p = w1p + (size_t)NE * FF * HD;                     // 1MB
    _Float16* wg_hi = (_Float16*)(w2p + (size_t)NE * FF * HD);
    _Float16* wg_lo = wg_hi + 8192;
    _Float16* wf_hi = wg_lo + 8192;
    _Float16* wf_lo = wf_hi + 4096;
    _Float16* wr_hi = wf_lo + 4096;
    _Float16* wr_lo = wr_hi + 1024;
    float*    gb2   = (float*)(wr_lo + 1024);              // [32]

    prep_router_kernel<<<7, 256, 0, stream>>>(
        geom_w, geom_b, ln_g, ln_b, fuse_w, router_w,
        wg_hi, wg_lo, wf_hi, wf_lo, wr_hi, wr_lo, gb2, (int*)d_ws);

    router5_kernel<<<N_TOK / 64, 256, 0, stream>>>(
        h, tok_emb, wg_hi, wg_lo, wf_hi, wf_lo, wr_hi, wr_lo,
        gb2, fuse_b, router_b, w1, w2, w1p, w2p,
        top_prob, order, counts, importance);

    expert_mfma_kernel<<<N_TOK / MT + NE + 1, 512, 0, stream>>>(
        h, w1p, w2p, b1, b2, top_prob, order, counts, importance, out);
}

// Round 14
// 205.911 us; speedup vs baseline: 1.2142x; 1.0113x over previous
//
#include <hip/hip_runtime.h>
#include <hip/hip_bf16.h>
#include <math.h>

#define N_TOK 131072
#define HD    256
#define DS    32
#define DG    32
#define FM    64
#define NE    4
#define FF    512
#define MT    64   // tokens per expert block (8 waves, 512 threads)

typedef short    short8 __attribute__((ext_vector_type(8)));
typedef _Float16 f16x8  __attribute__((ext_vector_type(8)));
typedef float    f32x4  __attribute__((ext_vector_type(4)));

struct F16Pair { _Float16 hi, lo; };

__device__ __forceinline__ float gelu_f(float x) {        // exact erf
    return 0.5f * x * (1.0f + erff(x * 0.70710678118654752f));
}
__device__ __forceinline__ unsigned short f2bf(float x) {
    union { __hip_bfloat16 b; unsigned short u; } cv;
    cv.b = __float2bfloat16(x);
    return cv.u;
}
__device__ __forceinline__ float bf2f(unsigned short u) {
    union { unsigned int i; float f; } cv;
    cv.i = (unsigned int)u << 16;
    return cv.f;
}
__device__ __forceinline__ F16Pair split16(float v) {
    F16Pair p;
    p.hi = (_Float16)v;
    p.lo = (_Float16)(v - (float)p.hi);
    return p;
}

// ---------------------------------------------------------------------------
// Prep-tables (7 blocks): router fp16 hi/lo tables + folded gb2 + ws zeroing.
// ---------------------------------------------------------------------------
__global__ __launch_bounds__(256) void prep_router_kernel(
    const float* __restrict__ geom_w, const float* __restrict__ geom_b,
    const float* __restrict__ ln_g, const float* __restrict__ ln_b,
    const float* __restrict__ fuse_w, const float* __restrict__ router_w,
    _Float16* __restrict__ wg_hi, _Float16* __restrict__ wg_lo,
    _Float16* __restrict__ wf_hi, _Float16* __restrict__ wf_lo,
    _Float16* __restrict__ wr_hi, _Float16* __restrict__ wr_lo,
    float* __restrict__ gb2, int* __restrict__ ws_zero)
{
    const int slot = blockIdx.x * 256 + threadIdx.x;
    const int lane = slot & 63;
    const int kg   = lane >> 4;
    const int row  = lane & 15;
    if (slot < 1024) {
        const int f = slot >> 6, ks = f >> 1, ni = f & 1;
        const int n = ni * 16 + row;
        f16x8 hi, lo;
        #pragma unroll
        for (int j = 0; j < 8; ++j) {
            int k = ks * 32 + kg * 8 + j;
            F16Pair p = split16(ln_g[k] * geom_w[k * DG + n]);
            hi[j] = p.hi; lo[j] = p.lo;
        }
        *reinterpret_cast<f16x8*>(&wg_hi[(size_t)slot * 8]) = hi;
        *reinterpret_cast<f16x8*>(&wg_lo[(size_t)slot * 8]) = lo;
    } else if (slot < 1536) {
        const int s = slot - 1024;
        const int f = s >> 6, ks = f >> 2, ni = f & 3;
        const int n = ni * 16 + row;
        f16x8 hi, lo;
        #pragma unroll
        for (int j = 0; j < 8; ++j) {
            int k = ks * 32 + kg * 8 + j;
            F16Pair p = split16(fuse_w[k * FM + n]);
            hi[j] = p.hi; lo[j] = p.lo;
        }
        *reinterpret_cast<f16x8*>(&wf_hi[(size_t)s * 8]) = hi;
        *reinterpret_cast<f16x8*>(&wf_lo[(size_t)s * 8]) = lo;
    } else if (slot < 1664) {
        const int s = slot - 1536;
        const int ks = s >> 6;
        f16x8 hi, lo;
        #pragma unroll
        for (int j = 0; j < 8; ++j) {
            int k = ks * 32 + kg * 8 + j;
            F16Pair p = split16((row < NE) ? router_w[k * NE + row] : 0.f);
            hi[j] = p.hi; lo[j] = p.lo;
        }
        *reinterpret_cast<f16x8*>(&wr_hi[(size_t)s * 8]) = hi;
        *reinterpret_cast<f16x8*>(&wr_lo[(size_t)s * 8]) = lo;
    } else if (slot < 1696) {
        const int n = slot - 1664;   // 0..31
        float acc = geom_b[n];
        for (int k = 0; k < HD; ++k) acc += ln_b[k] * geom_w[k * DG + n];
        gb2[n] = acc;
    } else if (slot < 1760) {
        ws_zero[slot - 1696] = 0;    // counts[4] + importance[4] + spare
    }
}

// ---------------------------------------------------------------------------
// Router v5: single-pass h (registers), MFMA fp16-split 3-term, fused
// bucketing, folded expert-weight repack (blocks 0..511). (verified r13)
// ---------------------------------------------------------------------------
__global__ __launch_bounds__(256) void router5_kernel(
    const float* __restrict__ h, const float* __restrict__ tok_emb,
    const _Float16* __restrict__ wg_hi, const _Float16* __restrict__ wg_lo,
    const _Float16* __restrict__ wf_hi, const _Float16* __restrict__ wf_lo,
    const _Float16* __restrict__ wr_hi, const _Float16* __restrict__ wr_lo,
    const float* __restrict__ gb2, const float* __restrict__ fuse_b,
    const float* __restrict__ router_b,
    const float* __restrict__ w1, const float* __restrict__ w2,
    unsigned short* __restrict__ w1p, unsigned short* __restrict__ w2p,
    float* __restrict__ top_prob, int* __restrict__ order,
    int* __restrict__ counts, float* __restrict__ importance)
{
    __shared__ __align__(16) _Float16 sg_hi[4][16][40], sg_lo[4][16][40];
    __shared__ __align__(16) _Float16 su_hi[4][16][72], su_lo[4][16][72];
    __shared__ __align__(16) float    s_lg[4][16][4];
    __shared__ float s_imp[NE];
    __shared__ int   s_cnt[NE];
    __shared__ int   s_base[NE];

    const int tid  = threadIdx.x;
    const int wv   = tid >> 6;
    const int lane = tid & 63;
    const int kg   = lane >> 4;
    const int row  = lane & 15;
    const int tok  = blockIdx.x * 64 + wv * 16 + row;

    if (tid < NE) { s_imp[tid] = 0.f; s_cnt[tid] = 0; }
    __syncthreads();

    // ---- single pass: load h into registers, stats, then split ----
    const float* hrow = h + (size_t)tok * HD;
    f32x4 v0[8], v1[8];
    float s1 = 0.f, s2 = 0.f;
    #pragma unroll
    for (int ks = 0; ks < 8; ++ks) {
        v0[ks] = *reinterpret_cast<const f32x4*>(hrow + ks * 32 + kg * 8);
        v1[ks] = *reinterpret_cast<const f32x4*>(hrow + ks * 32 + kg * 8 + 4);
        s1 += (v0[ks][0] + v0[ks][1]) + (v0[ks][2] + v0[ks][3])
            + (v1[ks][0] + v1[ks][1]) + (v1[ks][2] + v1[ks][3]);
        s2 += v0[ks][0]*v0[ks][0] + v0[ks][1]*v0[ks][1]
            + v0[ks][2]*v0[ks][2] + v0[ks][3]*v0[ks][3]
            + v1[ks][0]*v1[ks][0] + v1[ks][1]*v1[ks][1]
            + v1[ks][2]*v1[ks][2] + v1[ks][3]*v1[ks][3];
    }
    s1 += __shfl_xor(s1, 16); s1 += __shfl_xor(s1, 32);
    s2 += __shfl_xor(s2, 16); s2 += __shfl_xor(s2, 32);
    const float mu   = s1 * (1.0f / HD);
    const float var  = s2 * (1.0f / HD) - mu * mu;
    const float rstd = rsqrtf(var + 1e-5f);

    f16x8 ahi[8], alo[8];
    #pragma unroll
    for (int ks = 0; ks < 8; ++ks) {
        #pragma unroll
        for (int j = 0; j < 4; ++j) {
            F16Pair p = split16((v0[ks][j] - mu) * rstd);
            ahi[ks][j] = p.hi; alo[ks][j] = p.lo;
            F16Pair q = split16((v1[ks][j] - mu) * rstd);
            ahi[ks][4 + j] = q.hi; alo[ks][4 + j] = q.lo;
        }
    }

    const f16x8* WGH = reinterpret_cast<const f16x8*>(wg_hi);
    const f16x8* WGL = reinterpret_cast<const f16x8*>(wg_lo);
    f32x4 accg[2];
    #pragma unroll
    for (int ni = 0; ni < 2; ++ni) {
        float bb = gb2[ni * 16 + row];
        accg[ni] = (f32x4){bb, bb, bb, bb};
    }
    #pragma unroll
    for (int ks = 0; ks < 8; ++ks) {
        #pragma unroll
        for (int ni = 0; ni < 2; ++ni) {
            f16x8 bh = WGH[(ks * 2 + ni) * 64 + lane];
            f16x8 bl = WGL[(ks * 2 + ni) * 64 + lane];
            accg[ni] = __builtin_amdgcn_mfma_f32_16x16x32_f16(ahi[ks], bh, accg[ni], 0, 0, 0);
            accg[ni] = __builtin_amdgcn_mfma_f32_16x16x32_f16(alo[ks], bh, accg[ni], 0, 0, 0);
            accg[ni] = __builtin_amdgcn_mfma_f32_16x16x32_f16(ahi[ks], bl, accg[ni], 0, 0, 0);
        }
    }
    #pragma unroll
    for (int ni = 0; ni < 2; ++ni)
        #pragma unroll
        for (int r = 0; r < 4; ++r) {
            F16Pair p = split16(gelu_f(accg[ni][r]));
            sg_hi[wv][kg * 4 + r][ni * 16 + row] = p.hi;
            sg_lo[wv][kg * 4 + r][ni * 16 + row] = p.lo;
        }

    f16x8 a2h[2], a2l[2];
    {
        const float* terow = tok_emb + (size_t)tok * DS;
        float4 x0 = *reinterpret_cast<const float4*>(terow + kg * 8);
        float4 x1 = *reinterpret_cast<const float4*>(terow + kg * 8 + 4);
        float v[8] = {x0.x, x0.y, x0.z, x0.w, x1.x, x1.y, x1.z, x1.w};
        #pragma unroll
        for (int j = 0; j < 8; ++j) {
            F16Pair p = split16(v[j]);
            a2h[0][j] = p.hi; a2l[0][j] = p.lo;
        }
        a2h[1] = *reinterpret_cast<const f16x8*>(&sg_hi[wv][row][kg * 8]);
        a2l[1] = *reinterpret_cast<const f16x8*>(&sg_lo[wv][row][kg * 8]);
    }
    const f16x8* WFH = reinterpret_cast<const f16x8*>(wf_hi);
    const f16x8* WFL = reinterpret_cast<const f16x8*>(wf_lo);
    f32x4 accf[4];
    #pragma unroll
    for (int ni = 0; ni < 4; ++ni) {
        float bb = fuse_b[ni * 16 + row];
        accf[ni] = (f32x4){bb, bb, bb, bb};
    }
    #pragma unroll
    for (int ks = 0; ks < 2; ++ks) {
        #pragma unroll
        for (int ni = 0; ni < 4; ++ni) {
            f16x8 bh = WFH[(ks * 4 + ni) * 64 + lane];
            f16x8 bl = WFL[(ks * 4 + ni) * 64 + lane];
            accf[ni] = __builtin_amdgcn_mfma_f32_16x16x32_f16(a2h[ks], bh, accf[ni], 0, 0, 0);
            accf[ni] = __builtin_amdgcn_mfma_f32_16x16x32_f16(a2l[ks], bh, accf[ni], 0, 0, 0);
            accf[ni] = __builtin_amdgcn_mfma_f32_16x16x32_f16(a2h[ks], bl, accf[ni], 0, 0, 0);
        }
    }
    #pragma unroll
    for (int ni = 0; ni < 4; ++ni)
        #pragma unroll
        for (int r = 0; r < 4; ++r) {
            F16Pair p = split16(gelu_f(accf[ni][r]));
            su_hi[wv][kg * 4 + r][ni * 16 + row] = p.hi;
            su_lo[wv][kg * 4 + r][ni * 16 + row] = p.lo;
        }

    const f16x8* WRH = reinterpret_cast<const f16x8*>(wr_hi);
    const f16x8* WRL = reinterpret_cast<const f16x8*>(wr_lo);
    f32x4 accl = (f32x4){0.f, 0.f, 0.f, 0.f};
    #pragma unroll
    for (int ks = 0; ks < 2; ++ks) {
        f16x8 a3h = *reinterpret_cast<const f16x8*>(&su_hi[wv][row][ks * 32 + kg * 8]);
        f16x8 a3l = *reinterpret_cast<const f16x8*>(&su_lo[wv][row][ks * 32 + kg * 8]);
        f16x8 bh = WRH[ks * 64 + lane];
        f16x8 bl = WRL[ks * 64 + lane];
        accl = __builtin_amdgcn_mfma_f32_16x16x32_f16(a3h, bh, accl, 0, 0, 0);
        accl = __builtin_amdgcn_mfma_f32_16x16x32_f16(a3l, bh, accl, 0, 0, 0);
        accl = __builtin_amdgcn_mfma_f32_16x16x32_f16(a3h, bl, accl, 0, 0, 0);
    }
    if (row < NE) {
        float rb = router_b[row];
        #pragma unroll
        for (int r = 0; r < 4; ++r)
            s_lg[wv][kg * 4 + r][row] = accl[r] + rb;
    }
    __syncthreads();

    int bi = 0, rk = 0, gt = 0;
    if (lane < 16) {
        float4 lg = *reinterpret_cast<const float4*>(&s_lg[wv][lane][0]);
        float m  = fmaxf(fmaxf(lg.x, lg.y), fmaxf(lg.z, lg.w));
        float e0 = expf(lg.x - m), e1 = expf(lg.y - m),
              e2 = expf(lg.z - m), e3 = expf(lg.w - m);
        float inv = 1.0f / (e0 + e1 + e2 + e3);
        float p0 = e0 * inv, p1 = e1 * inv, p2 = e2 * inv, p3 = e3 * inv;
        float bp = p0;
        if (p1 > bp) { bp = p1; bi = 1; }
        if (p2 > bp) { bp = p2; bi = 2; }
        if (p3 > bp) { bp = p3; bi = 3; }
        gt = blockIdx.x * 64 + wv * 16 + lane;
        top_prob[gt] = bp;
        rk = atomicAdd(&s_cnt[bi], 1);
        atomicAdd(&s_imp[0], p0); atomicAdd(&s_imp[1], p1);
        atomicAdd(&s_imp[2], p2); atomicAdd(&s_imp[3], p3);
    }
    __syncthreads();
    if (tid < NE) {
        s_base[tid] = atomicAdd(&counts[tid], s_cnt[tid]);  // reserve + count
        atomicAdd(&importance[tid], s_imp[tid]);
    }
    __syncthreads();
    if (lane < 16)
        order[bi * N_TOK + s_base[bi] + rk] = gt;

    // ---- folded expert-weight repack (consumed by next launch only) ------
    if (blockIdx.x < 512) {
        int t = (blockIdx.x & 255) * 256 + tid;
        const int pl  = t & 63;
        const int pkg = pl >> 4;
        const int prw = pl & 15;
        if (blockIdx.x < 256) {
            const int ni = (t >> 6) & 31;
            const int ks = (t >> 11) & 7;
            const int e  = t >> 14;
            const int n  = ni * 16 + prw;
            const int k0 = ks * 32 + pkg * 8;
            short8 o;
            #pragma unroll
            for (int j = 0; j < 8; ++j)
                o[j] = (short)f2bf(w1[((size_t)e * HD + k0 + j) * FF + n]);
            *reinterpret_cast<short8*>(&w1p[(size_t)(((e*8 + ks)*32 + ni)*64 + pl) * 8]) = o;
        } else {
            const int ni = (t >> 6) & 15;
            const int ks = (t >> 10) & 15;
            const int e  = t >> 14;
            const int n  = ni * 16 + prw;
            const int k0 = ks * 32 + pkg * 8;
            short8 o;
            #pragma unroll
            for (int j = 0; j < 8; ++j)
                o[j] = (short)f2bf(w2[((size_t)e * FF + k0 + j) * HD + n]);
            *reinterpret_cast<short8*>(&w2p[(size_t)(((e*16 + ks)*16 + ni)*64 + pl) * 8]) = o;
        }
    }
}

// ---------------------------------------------------------------------------
// Expert FFN v9: round-13 structure + conflict-free gather (LDS slot index
// == linear thread index; decode (row,kg,mi,ks) from slot). Same layout.
// ---------------------------------------------------------------------------
__global__ __launch_bounds__(512, 6) void expert_mfma_kernel(
    const float* __restrict__ h,
    const unsigned short* __restrict__ w1p,
    const unsigned short* __restrict__ w2p,
    const float* __restrict__ b1, const float* __restrict__ b2,
    const float* __restrict__ top_prob,
    const int* __restrict__ order, const int* __restrict__ counts,
    const float* __restrict__ importance, float* __restrict__ out)
{
    __shared__ __align__(16) unsigned short sh_h[8 * 4 * 512];   // 32 KB
    __shared__ __align__(16) unsigned short sh_a[4 * 4 * 512];   // 16 KB
    __shared__ int s_tok[MT];

    const int tid = threadIdx.x;

    if (blockIdx.x == N_TOK / MT + NE) {      // lb block
        if (tid == 0) {
            double num = (double)importance[0] * counts[0] +
                         (double)importance[1] * counts[1] +
                         (double)importance[2] * counts[2] +
                         (double)importance[3] * counts[3];
            out[(size_t)N_TOK * HD] =
                (float)((double)NE * num / ((double)N_TOK * (double)N_TOK + 1e-8));
        }
        return;
    }

    int c = blockIdx.x, e;
    for (e = 0; e < NE; ++e) {
        int nch = (counts[e] + MT - 1) / MT;
        if (c < nch) break;
        c -= nch;
    }
    if (e >= NE) return;
    const int cnt  = counts[e];
    const int base = e * N_TOK + c * MT;
    const int nt   = min(MT, cnt - c * MT);

    if (tid < MT) s_tok[tid] = (tid < nt) ? order[base + tid] : -1;
    __syncthreads();

    // gather: s = LDS slot index (linear per thread -> conflict-free writes)
    #pragma unroll
    for (int it = 0; it < 4; ++it) {
        int s   = tid + it * 512;           // 0..2047
        int row = s & 15;
        int kgq = (s >> 4) & 3;
        int mi  = (s >> 6) & 3;
        int ks  = s >> 8;
        int tr  = mi * 16 + row;
        int q   = ks * 4 + kgq;
        int t   = s_tok[tr];
        float4 v0 = make_float4(0.f,0.f,0.f,0.f), v1 = v0;
        if (t >= 0) {
            const float* p = &h[(size_t)t * HD + q * 8];
            v0 = *reinterpret_cast<const float4*>(p);
            v1 = *reinterpret_cast<const float4*>(p + 4);
        }
        short8 o;
        o[0] = (short)f2bf(v0.x); o[1] = (short)f2bf(v0.y);
        o[2] = (short)f2bf(v0.z); o[3] = (short)f2bf(v0.w);
        o[4] = (short)f2bf(v1.x); o[5] = (short)f2bf(v1.y);
        o[6] = (short)f2bf(v1.z); o[7] = (short)f2bf(v1.w);
        *reinterpret_cast<short8*>(&sh_h[(size_t)s * 8]) = o;
    }
    __syncthreads();

    const int lane  = tid & 63;
    const int wv    = tid >> 6;       // 0..7
    const int row15 = lane & 15;
    const int kg    = lane >> 4;

    const unsigned short* W1 = w1p + (size_t)e * 8 * 32 * 512;
    const unsigned short* W2 = w2p + (size_t)e * 16 * 16 * 512;

    f32x4 acc2[2][4];
    #pragma unroll
    for (int ni = 0; ni < 2; ++ni) {
        f32x4 bb = *reinterpret_cast<const f32x4*>(&b2[e * HD + wv * 32 + ni * 16 + kg * 4]);
        #pragma unroll
        for (int mi = 0; mi < 4; ++mi) acc2[ni][mi] = bb;
    }

    const int l_w   = wv >> 1;
    const int kg2_w = (wv & 1) * 2 + (kg >> 1);

    #pragma unroll
    for (int p = 0; p < 4; ++p) {
        f32x4 acc1[4];
        {
            f32x4 bb = *reinterpret_cast<const f32x4*>(
                &b1[e * FF + p * 128 + wv * 16 + kg * 4]);
            #pragma unroll
            for (int mi = 0; mi < 4; ++mi) acc1[mi] = bb;
        }
        #pragma unroll
        for (int ks = 0; ks < 8; ++ks) {
            short8 bh[4];
            #pragma unroll
            for (int mi = 0; mi < 4; ++mi)
                bh[mi] = *reinterpret_cast<const short8*>(&sh_h[((ks*4 + mi)*64 + lane) * 8]);
            short8 aw = *reinterpret_cast<const short8*>(
                &W1[(size_t)((ks*32 + p*8 + wv)*64 + lane) * 8]);
            #pragma unroll
            for (int mi = 0; mi < 4; ++mi)
                acc1[mi] = __builtin_amdgcn_mfma_f32_16x16x32_bf16(aw, bh[mi], acc1[mi], 0, 0, 0);
        }
        if (p > 0) __syncthreads();    // pass p-1's sh_a reads complete

        #pragma unroll
        for (int mi = 0; mi < 4; ++mi) {
            ushort4 pk;
            pk.x = f2bf(gelu_f(acc1[mi][0]));
            pk.y = f2bf(gelu_f(acc1[mi][1]));
            pk.z = f2bf(gelu_f(acc1[mi][2]));
            pk.w = f2bf(gelu_f(acc1[mi][3]));
            *reinterpret_cast<ushort4*>(
                &sh_a[(((l_w*4 + mi)*64 + kg2_w*16 + row15) * 8 + (kg & 1) * 4)]) = pk;
        }
        __syncthreads();

        #pragma unroll
        for (int l2 = 0; l2 < 4; ++l2) {
            short8 ba[4];
            #pragma unroll
            for (int mi = 0; mi < 4; ++mi)
                ba[mi] = *reinterpret_cast<const short8*>(&sh_a[((l2*4 + mi)*64 + lane) * 8]);
            #pragma unroll
            for (int ni = 0; ni < 2; ++ni) {
                short8 aw = *reinterpret_cast<const short8*>(
                    &W2[(size_t)(((p*4 + l2)*16 + wv*2 + ni)*64 + lane) * 8]);
                #pragma unroll
                for (int mi = 0; mi < 4; ++mi)
                    acc2[ni][mi] = __builtin_amdgcn_mfma_f32_16x16x32_bf16(aw, ba[mi], acc2[ni][mi], 0, 0, 0);
            }
        }
    }

    // epilogue: residual from sh_h (bf16) — no global h re-read
    #pragma unroll
    for (int mi = 0; mi < 4; ++mi) {
        int gt = s_tok[mi * 16 + row15];
        if (gt < 0) continue;
        float tp = 0.5f * top_prob[gt];
        #pragma unroll
        for (int ni = 0; ni < 2; ++ni) {
            int nb = wv * 32 + ni * 16 + kg * 4;
            ushort4 rb = *reinterpret_cast<const ushort4*>(
                &sh_h[((wv*4 + mi)*64 + (ni*2 + (kg >> 1))*16 + row15) * 8 + (kg & 1) * 4]);
            float4 o;
            o.x = bf2f(rb.x) + tp * acc2[ni][mi][0];
            o.y = bf2f(rb.y) + tp * acc2[ni][mi][1];
            o.z = bf2f(rb.z) + tp * acc2[ni][mi][2];
            o.w = bf2f(rb.w) + tp * acc2[ni][mi][3];
            *reinterpret_cast<float4*>(&out[(size_t)gt * HD + nb]) = o;
        }
    }
}

// ---------------------------------------------------------------------------
extern "C" void kernel_launch(void* const* d_in, const int* in_sizes, int n_in,
                              void* d_out, int out_size, void* d_ws, size_t ws_size,
                              hipStream_t stream)
{
    const float* h        = (const float*)d_in[0];
    const float* tok_emb  = (const float*)d_in[1];
    /* d_in[2] = is_mask: all zeros, unused by the reference math */
    const float* ln_g     = (const float*)d_in[3];
    const float* ln_b     = (const float*)d_in[4];
    const float* geom_w   = (const float*)d_in[5];
    const float* geom_b   = (const float*)d_in[6];
    const float* fuse_w   = (const float*)d_in[7];
    const float* fuse_b   = (const float*)d_in[8];
    const float* router_w = (const float*)d_in[9];
    const float* router_b = (const float*)d_in[10];
    const float* w1       = (const float*)d_in[11];
    const float* b1       = (const float*)d_in[12];
    const float* w2       = (const float*)d_in[13];
    const float* b2       = (const float*)d_in[14];
    float* out = (float*)d_out;

    // workspace layout (4B word units from d_ws)
    int*   counts     = (int*)d_ws;                        // [4]
    float* importance = (float*)d_ws + 4;                  // [4]
    float* top_prob   = (float*)d_ws + 64;                 // [N]
    int*   order      = (int*)d_ws + 64 + N_TOK;           // [4*N] regions
    unsigned short* w1p = (unsigned short*)((int*)d_ws + 64 + 5 * N_TOK); // 1MB
    unsigned short* w2p = w1p + (size_t)NE * FF * HD;                     // 1MB
    _Float16* wg_hi = (_Float16*)(w2p + (size_t)NE * FF * HD);
    _Float16* wg_lo = wg_hi + 8192;
    _Float16* wf_hi = wg_lo + 8192;
    _Float16* wf_lo = wf_hi + 4096;
    _Float16* wr_hi = wf_lo + 4096;
    _Float16* wr_lo = wr_hi + 1024;
    float*    gb2   = (float*)(wr_lo + 1024);              // [32]

    prep_router_kernel<<<7, 256, 0, stream>>>(
        geom_w, geom_b, ln_g, ln_b, fuse_w, router_w,
        wg_hi, wg_lo, wf_hi, wf_lo, wr_hi, wr_lo, gb2, (int*)d_ws);

    router5_kernel<<<N_TOK / 64, 256, 0, stream>>>(
        h, tok_emb, wg_hi, wg_lo, wf_hi, wf_lo, wr_hi, wr_lo,
        gb2, fuse_b, router_b, w1, w2, w1p, w2p,
        top_prob, order, counts, importance);

    expert_mfma_kernel<<<N_TOK / MT + NE + 1, 512, 0, stream>>>(
        h, w1p, w2p, b1, b2, top_prob, order, counts, importance, out);
}